// Round 4
// baseline (631.970 us; speedup 1.0000x reference)
//
#include <hip/hip_runtime.h>
#include <hip/hip_bf16.h>

#define EMBED 1024
#define HEADS 16
#define HD 64
#define NVTOK 4096
#define NLTOK 256
#define BATCH 4
#define QSCALE 0.25f   // HEADS**-0.5

typedef __hip_bfloat16 bf16;
typedef __attribute__((ext_vector_type(8))) short bf16x8;
typedef __attribute__((ext_vector_type(4))) float floatx4;

#define MFMA(a, b, c) __builtin_amdgcn_mfma_f32_16x16x32_bf16((a), (b), (c), 0, 0, 0)

static __device__ __forceinline__ short f2bs(float x) {
  bf16 h = __float2bfloat16(x);
  return *reinterpret_cast<short*>(&h);
}
static __device__ __forceinline__ float b2f(bf16 x) { return __bfloat162float(x); }

// Async global->LDS, 16B per lane. LDS dest = wave-uniform base + lane*16.
typedef const __attribute__((address_space(1))) char ga_char;
typedef __attribute__((address_space(3))) char ls_char;
static __device__ __forceinline__ void load_lds16(const void* g, void* lds) {
  __builtin_amdgcn_global_load_lds((ga_char*)g, (ls_char*)(unsigned)(size_t)(lds), 16, 0, 0);
}

// ---------------------------------------------------------------------------
// Input dtype detector (fp32 vs bf16 packed). flag[0]=1 => fp32.
// flag[1] = constant 0 (bf16-output selector for internal GEMMs).
// ---------------------------------------------------------------------------
__global__ void detect_dtype(const unsigned* __restrict__ v, int* __restrict__ flag) {
  __shared__ int cnt;
  if (threadIdx.x == 0) cnt = 0;
  __syncthreads();
  unsigned u = v[threadIdx.x];
  int mid = (int)((u >> 7) & 0xFF);
  if (mid >= 110 && mid <= 140) atomicAdd(&cnt, 1);
  __syncthreads();
  if (threadIdx.x == 0) {
    flag[0] = (cnt < 192) ? 1 : 0;
    flag[1] = 0;
  }
}

// ---------------------------------------------------------------------------
// Vectorized input convert (4 elements/thread). n4 = n/4.
// ---------------------------------------------------------------------------
__global__ void convert_to_bf16_v4(const void* __restrict__ src, bf16* __restrict__ dst,
                                   int n4, const int* __restrict__ flag) {
  int i = blockIdx.x * 256 + threadIdx.x;
  if (i >= n4) return;
  short4 o;
  if (flag[0]) {
    float4 f = ((const float4*)src)[i];
    o.x = f2bs(f.x); o.y = f2bs(f.y); o.z = f2bs(f.z); o.w = f2bs(f.w);
  } else {
    o = ((const short4*)src)[i];
  }
  ((short4*)dst)[i] = o;
}

// Batched weight convert+transpose (+ per-weight scale): src [R][C] -> dst [C][R].
struct WTArgs {
  const void* src[6];
  bf16* dst[6];
  int R[6];
  int C[6];
  float scale[6];
};
__global__ __launch_bounds__(256) void convert_transpose_all(WTArgs a, const int* __restrict__ flag) {
  __shared__ float tile[32][33];
  const int z = blockIdx.y;
  const int R = a.R[z], C = a.C[z];
  const float sc = a.scale[z];
  const int tpc = C >> 5;
  const int nt = (R >> 5) * tpc;
  const int t = blockIdx.x;
  if (t >= nt) return;
  const int r0 = (t / tpc) << 5, c0 = (t % tpc) << 5;
  {
    const int row = threadIdx.x >> 3, cg = (threadIdx.x & 7) << 2;
    if (flag[0]) {
      float4 f = *(const float4*)((const float*)a.src[z] + (size_t)(r0 + row) * C + c0 + cg);
      tile[row][cg] = f.x * sc; tile[row][cg + 1] = f.y * sc;
      tile[row][cg + 2] = f.z * sc; tile[row][cg + 3] = f.w * sc;
    } else {
      short4 f = *(const short4*)((const short*)a.src[z] + (size_t)(r0 + row) * C + c0 + cg);
      tile[row][cg]     = b2f(*(const bf16*)&f.x) * sc;
      tile[row][cg + 1] = b2f(*(const bf16*)&f.y) * sc;
      tile[row][cg + 2] = b2f(*(const bf16*)&f.z) * sc;
      tile[row][cg + 3] = b2f(*(const bf16*)&f.w) * sc;
    }
  }
  __syncthreads();
  {
    const int col = threadIdx.x >> 3, rg = (threadIdx.x & 7) << 2;
    short4 o;
    o.x = f2bs(tile[rg + 0][col]);
    o.y = f2bs(tile[rg + 1][col]);
    o.z = f2bs(tile[rg + 2][col]);
    o.w = f2bs(tile[rg + 3][col]);
    *(short4*)((short*)a.dst[z] + (size_t)(c0 + col) * R + r0 + rg) = o;
  }
}

// Batched bias convert (+ scale).
struct BArgs {
  const void* src[6];
  bf16* dst[6];
  int n[6];
  float scale[6];
};
__global__ void convert_bias_all(BArgs a, const int* __restrict__ flag) {
  int z = blockIdx.y;
  int i = blockIdx.x * 256 + threadIdx.x;
  if (i >= a.n[z]) return;
  float x = flag[0] ? ((const float*)a.src[z])[i] : b2f(((const bf16*)a.src[z])[i]);
  a.dst[z][i] = __float2bfloat16(x * a.scale[z]);
}

// ---------------------------------------------------------------------------
// val_l per-head transpose: vl = kv[:, 1024:2048] -> vlT [B*H][HD][NL]
// ---------------------------------------------------------------------------
__global__ __launch_bounds__(256) void transpose_vl_heads(const bf16* __restrict__ kv,
                                                          bf16* __restrict__ vlT) {
  __shared__ short t[64][72];
  const int bh = blockIdx.y, b = bh >> 4, h = bh & 15;
  const int nl0 = blockIdx.x << 6;
  const int tid = threadIdx.x;
  {
    const int nl = tid >> 2, dg = (tid & 3) << 4;
    const short* s = (const short*)kv + ((size_t)b * NLTOK + nl0 + nl) * 2048 + 1024 + h * HD + dg;
    *(bf16x8*)&t[nl][dg]     = *(const bf16x8*)s;
    *(bf16x8*)&t[nl][dg + 8] = *(const bf16x8*)(s + 8);
  }
  __syncthreads();
  {
    const int d = tid >> 2, ng = (tid & 3) << 4;
    short* o = (short*)vlT + ((size_t)bh * HD + d) * NLTOK + nl0 + ng;
    short tmp[16];
#pragma unroll
    for (int j = 0; j < 16; j++) tmp[j] = t[ng + j][d];
    *(bf16x8*)o       = *(bf16x8*)&tmp[0];
    *(bf16x8*)(o + 8) = *(bf16x8*)&tmp[8];
  }
}

// ---------------------------------------------------------------------------
// Small NT GEMM (m97 128x128 pattern, BK=64, LDS-staged coalesced epilogue).
// Used for the small l-side GEMMs only.
// ---------------------------------------------------------------------------
__global__ __launch_bounds__(256) void gemm_nt(
    const bf16* __restrict__ A, const bf16* __restrict__ Bt,
    const bf16* __restrict__ bias, void* __restrict__ Cout, long long coff,
    int M, int N, int K, float alpha, const int* __restrict__ outf) {
  __shared__ short lds_all[16896];
  short* As = lds_all;
  short* Bs = lds_all + 8192;
  const int f32o = outf[0];
  const int tid = threadIdx.x;
  const int wave = tid >> 6, lane = tid & 63;
  const int bm = blockIdx.x * 128, bn = blockIdx.y * 128;
  const int wr = (wave & 1) * 64, wc = (wave >> 1) * 64;
  const int rl = lane & 15, kg = (lane >> 4) * 8;

  const int srow = wave * 16 + (lane >> 2);
  const int scol = (lane & 3) * 8;
  const short* Ag = (const short*)A + (size_t)(bm + srow) * K + scol;
  const short* Bg = (const short*)Bt + (size_t)(bn + srow) * K + scol;
  short* As0l = &As[wave * 512];
  short* As1l = &As[2048 + wave * 512];
  short* As0h = &As[4096 + wave * 512];
  short* As1h = &As[6144 + wave * 512];
  short* Bs0l = &Bs[wave * 512];
  short* Bs1l = &Bs[2048 + wave * 512];
  short* Bs0h = &Bs[4096 + wave * 512];
  short* Bs1h = &Bs[6144 + wave * 512];
  const size_t rstep = (size_t)64 * K;

  floatx4 acc[4][4];
#pragma unroll
  for (int i = 0; i < 4; i++)
#pragma unroll
    for (int j = 0; j < 4; j++) acc[i][j] = (floatx4){0.f, 0.f, 0.f, 0.f};

  for (int k0 = 0; k0 < K; k0 += 64) {
    __syncthreads();
    load_lds16(Ag + k0, As0l);
    load_lds16(Ag + rstep + k0, As1l);
    load_lds16(Ag + k0 + 32, As0h);
    load_lds16(Ag + rstep + k0 + 32, As1h);
    load_lds16(Bg + k0, Bs0l);
    load_lds16(Bg + rstep + k0, Bs1l);
    load_lds16(Bg + k0 + 32, Bs0h);
    load_lds16(Bg + rstep + k0 + 32, Bs1h);
    __syncthreads();
#pragma unroll
    for (int half = 0; half < 2; half++) {
      const short* Ah = &As[half * 4096];
      const short* Bh = &Bs[half * 4096];
      bf16x8 af[4], bfr[4];
#pragma unroll
      for (int i = 0; i < 4; i++) af[i]  = *(const bf16x8*)&Ah[(wr + i * 16 + rl) * 32 + kg];
#pragma unroll
      for (int j = 0; j < 4; j++) bfr[j] = *(const bf16x8*)&Bh[(wc + j * 16 + rl) * 32 + kg];
#pragma unroll
      for (int i = 0; i < 4; i++)
#pragma unroll
        for (int j = 0; j < 4; j++) acc[i][j] = MFMA(af[i], bfr[j], acc[i][j]);
    }
  }

  const int rg = (lane >> 4) * 4;
  __syncthreads();  // all K-loop LDS reads done; reuse lds_all for C staging

  if (!f32o) {
#pragma unroll
    for (int j = 0; j < 4; j++) {
      float bv = b2f(bias[bn + wc + j * 16 + rl]);
#pragma unroll
      for (int i = 0; i < 4; i++)
#pragma unroll
        for (int r = 0; r < 4; r++)
          lds_all[(wr + i * 16 + rg + r) * 132 + wc + j * 16 + rl] =
              f2bs((acc[i][j][r] + bv) * alpha);
    }
    __syncthreads();
#pragma unroll
    for (int it = 0; it < 8; it++) {
      int idx = it * 256 + tid;
      int row = idx >> 4, c = idx & 15;
      bf16x8 o = *(const bf16x8*)&lds_all[row * 132 + c * 8];
      *(bf16x8*)((short*)Cout + coff + (long long)(bm + row) * N + bn + c * 8) = o;
    }
  } else {
    float* Cf = (float*)lds_all;
#pragma unroll
    for (int p = 0; p < 2; p++) {
      if ((wave & 1) == p) {
#pragma unroll
        for (int j = 0; j < 4; j++) {
          float bv = b2f(bias[bn + wc + j * 16 + rl]);
#pragma unroll
          for (int i = 0; i < 4; i++)
#pragma unroll
            for (int r = 0; r < 4; r++)
              Cf[(i * 16 + rg + r) * 132 + wc + j * 16 + rl] = (acc[i][j][r] + bv) * alpha;
        }
      }
      __syncthreads();
#pragma unroll
      for (int it = 0; it < 8; it++) {
        int idx = it * 256 + tid;
        int row = idx >> 5, c = idx & 31;
        float4 o = *(const float4*)&Cf[row * 132 + c * 4];
        *(float4*)((float*)Cout + coff + (long long)(bm + p * 64 + row) * N + bn + c * 4) = o;
      }
      if (p == 0) __syncthreads();
    }
  }
}

// ---------------------------------------------------------------------------
// Big NT GEMM: 256x256 tile, BK=64, 512 threads (8 waves = 2M x 4N), deep
// pipeline (T3+T4): double-buffered 128KiB LDS, global_load_lds staging with
// counted vmcnt(8) -- NEVER drained to 0 in the main loop -- so one K-tile's
// loads stay in flight across barriers. Per K-tile: 4 quadrant-phases of
// {ds_reads; s_barrier; lgkmcnt(0)+sched_barrier (rule 18); setprio(1);
// 16 MFMA; setprio(0); s_barrier} (T5 role-split). Raw s_barrier everywhere
// in the loop (no __syncthreads -> no implicit vmcnt(0) drain).
// LDS read swizzle (T2, rule 21 both-sides): LDS dest linear (gload_lds
// requirement); SOURCE col-group pre-XORed by row&7; reads XOR identically.
// Element trace: lds_unit(row,slot) = global cg = slot^(row&7) both sides.
// XCD-aware bijective block swizzle (m204) so each XCD sweeps one N-column.
// Requires: M,N multiples of 256; K multiple of 128.
// ---------------------------------------------------------------------------
#define VMCNT8() do { asm volatile("s_waitcnt vmcnt(8)" ::: "memory"); \
                      __builtin_amdgcn_sched_barrier(0); } while (0)
#define VMCNT0() do { asm volatile("s_waitcnt vmcnt(0)" ::: "memory"); \
                      __builtin_amdgcn_sched_barrier(0); } while (0)
#define P_PRE()  do { __builtin_amdgcn_s_barrier(); \
                      asm volatile("s_waitcnt lgkmcnt(0)" ::: "memory"); \
                      __builtin_amdgcn_sched_barrier(0); \
                      __builtin_amdgcn_s_setprio(1); } while (0)
#define P_POST() do { __builtin_amdgcn_s_setprio(0); \
                      __builtin_amdgcn_sched_barrier(0); \
                      __builtin_amdgcn_s_barrier(); } while (0)

static __device__ __forceinline__ void compute_tile256(
    const short* __restrict__ Ab, const short* __restrict__ Bb,
    floatx4 (&acc)[8][4], int wm, int wn, int rl, int lg) {
  const int sw = rl & 7;
  bf16x8 a[4][2], b0[2][2], b1[2][2];
#define LDA256(m, kk) (*(const bf16x8*)&Ab[(wm * 128 + (m) * 16 + rl) * 64 + ((((kk) * 4 + lg) ^ sw) * 8)])
#define LDB256(n, kk) (*(const bf16x8*)&Bb[(wn * 64 + (n) * 16 + rl) * 64 + ((((kk) * 4 + lg) ^ sw) * 8)])
  // P1: read A(m0-3), B(n0-1); MFMA quadrant (m0-3, n0-1)
#pragma unroll
  for (int m = 0; m < 4; m++) { a[m][0] = LDA256(m, 0); a[m][1] = LDA256(m, 1); }
#pragma unroll
  for (int n = 0; n < 2; n++) { b0[n][0] = LDB256(n, 0); b0[n][1] = LDB256(n, 1); }
  P_PRE();
#pragma unroll
  for (int m = 0; m < 4; m++)
#pragma unroll
    for (int n = 0; n < 2; n++) {
      acc[m][n] = MFMA(a[m][0], b0[n][0], acc[m][n]);
      acc[m][n] = MFMA(a[m][1], b0[n][1], acc[m][n]);
    }
  P_POST();
  // P2: read B(n2-3); MFMA (m0-3, n2-3)
#pragma unroll
  for (int n = 0; n < 2; n++) { b1[n][0] = LDB256(n + 2, 0); b1[n][1] = LDB256(n + 2, 1); }
  P_PRE();
#pragma unroll
  for (int m = 0; m < 4; m++)
#pragma unroll
    for (int n = 0; n < 2; n++) {
      acc[m][n + 2] = MFMA(a[m][0], b1[n][0], acc[m][n + 2]);
      acc[m][n + 2] = MFMA(a[m][1], b1[n][1], acc[m][n + 2]);
    }
  P_POST();
  // P3: read A(m4-7); MFMA (m4-7, n2-3)
#pragma unroll
  for (int m = 0; m < 4; m++) { a[m][0] = LDA256(m + 4, 0); a[m][1] = LDA256(m + 4, 1); }
  P_PRE();
#pragma unroll
  for (int m = 0; m < 4; m++)
#pragma unroll
    for (int n = 0; n < 2; n++) {
      acc[m + 4][n + 2] = MFMA(a[m][0], b1[n][0], acc[m + 4][n + 2]);
      acc[m + 4][n + 2] = MFMA(a[m][1], b1[n][1], acc[m + 4][n + 2]);
    }
  P_POST();
  // P4: no reads; MFMA (m4-7, n0-1) reusing b0
  P_PRE();
#pragma unroll
  for (int m = 0; m < 4; m++)
#pragma unroll
    for (int n = 0; n < 2; n++) {
      acc[m + 4][n] = MFMA(a[m][0], b0[n][0], acc[m + 4][n]);
      acc[m + 4][n] = MFMA(a[m][1], b0[n][1], acc[m + 4][n]);
    }
  P_POST();
#undef LDA256
#undef LDB256
}

__global__ __launch_bounds__(512, 2) void gemm256_nt(
    const bf16* __restrict__ A, const bf16* __restrict__ Bt,
    const bf16* __restrict__ bias, void* __restrict__ Cout, long long coff,
    int M, int N, int K, float alpha, const int* __restrict__ outf) {
  extern __shared__ short lds[];  // 131072 B
  short* A0 = lds;
  short* B0 = lds + 16384;
  short* A1 = lds + 32768;
  short* B1 = lds + 49152;
  const int f32o = outf[0];
  const int tid = threadIdx.x;
  const int wave = tid >> 6, lane = tid & 63;
  const int rl = lane & 15, lg = lane >> 4;
  const int wm = wave >> 2, wn = wave & 3;

  // XCD-aware bijective swizzle (m204) on the flat block id; mt-fastest.
  const int nwg = gridDim.x;
  const int nMT = M >> 8;
  {
  }
  int orig = blockIdx.x;
  int qq = nwg >> 3, rr = nwg & 7, xcd = orig & 7, sidx = orig >> 3;
  int swz = (xcd < rr) ? (xcd * (qq + 1) + sidx)
                       : (rr * (qq + 1) + (xcd - rr) * qq + sidx);
  const int bm = (swz % nMT) * 256;
  const int bn = (swz / nMT) * 256;

  // staging addresses (per-lane global, wave-uniform LDS base; source
  // col-group pre-swizzled: cg = (l&7) ^ (l>>3) so that
  // lds_unit(row, slot) holds global(row, slot ^ (row & 7)))
  const int r8 = lane >> 3;
  const int cgs = (lane & 7) ^ r8;
  const short* ga = (const short*)A + (size_t)(bm + wave * 8 + r8) * K + cgs * 8;
  const short* gb = (const short*)Bt + (size_t)(bn + wave * 8 + r8) * K + cgs * 8;

#define STAGE256(LA, LB, k0_) do {                                          \
    _Pragma("unroll")                                                       \
    for (int p = 0; p < 4; p++) {                                           \
      load_lds16(ga + (size_t)(p * 64) * K + (k0_), (LA) + wave * 512 + p * 4096); \
      load_lds16(gb + (size_t)(p * 64) * K + (k0_), (LB) + wave * 512 + p * 4096); \
    }                                                                       \
  } while (0)

  floatx4 acc[8][4];
#pragma unroll
  for (int m = 0; m < 8; m++)
#pragma unroll
    for (int n = 0; n < 4; n++) acc[m][n] = (floatx4){0.f, 0.f, 0.f, 0.f};

  const int NT = K >> 6;  // even (K multiple of 128)
  STAGE256(A0, B0, 0);
  STAGE256(A1, B1, 64);
  int kt = 0;
  for (; kt + 2 < NT; kt += 2) {
    VMCNT8();  // tile kt landed (tile kt+1's 8 loads still in flight)
    __builtin_amdgcn_s_barrier();
    compute_tile256(A0, B0, acc, wm, wn, rl, lg);
    STAGE256(A0, B0, (kt + 2) * 64);  // safe: P4's trailing barrier = reads done
    VMCNT8();
    __builtin_amdgcn_s_barrier();
    compute_tile256(A1, B1, acc, wm, wn, rl, lg);
    STAGE256(A1, B1, (kt + 3) * 64);
  }
  VMCNT8();
  __builtin_amdgcn_s_barrier();
  compute_tile256(A0, B0, acc, wm, wn, rl, lg);
  VMCNT0();
  __builtin_amdgcn_s_barrier();
  compute_tile256(A1, B1, acc, wm, wn, rl, lg);
  __syncthreads();  // epilogue boundary; vmcnt already 0

  // Epilogue: stage C through LDS (reusing the 128KB), fully coalesced 16B stores.
  if (!f32o) {
    // two 128-row passes, stride 264 shorts
#pragma unroll
    for (int p = 0; p < 2; p++) {
      if (wm == p) {
#pragma unroll
        for (int n = 0; n < 4; n++) {
          float bv = b2f(bias[bn + wn * 64 + n * 16 + rl]);
#pragma unroll
          for (int m = 0; m < 8; m++)
#pragma unroll
            for (int r2 = 0; r2 < 4; r2++)
              lds[(m * 16 + lg * 4 + r2) * 264 + wn * 64 + n * 16 + rl] =
                  f2bs((acc[m][n][r2] + bv) * alpha);
        }
      }
      __syncthreads();
#pragma unroll
      for (int it = 0; it < 8; it++) {
        int idx2 = it * 512 + tid;
        int row = idx2 >> 5, c = idx2 & 31;
        bf16x8 o = *(const bf16x8*)&lds[row * 264 + c * 8];
        *(bf16x8*)((short*)Cout + coff + (long long)(bm + p * 128 + row) * N + bn + c * 8) = o;
      }
      __syncthreads();
    }
  } else {
    // four 64-row passes, stride 260 floats
    float* Cf = (float*)lds;
#pragma unroll
    for (int p = 0; p < 4; p++) {
      if (wm == (p >> 1)) {
#pragma unroll
        for (int n = 0; n < 4; n++) {
          float bv = b2f(bias[bn + wn * 64 + n * 16 + rl]);
#pragma unroll
          for (int mm = 0; mm < 4; mm++)
#pragma unroll
            for (int r2 = 0; r2 < 4; r2++)
              Cf[(mm * 16 + lg * 4 + r2) * 260 + wn * 64 + n * 16 + rl] =
                  (acc[(p & 1) * 4 + mm][n][r2] + bv) * alpha;
        }
      }
      __syncthreads();
#pragma unroll
      for (int it = 0; it < 8; it++) {
        int idx2 = it * 512 + tid;
        int row = idx2 >> 6, c = idx2 & 63;
        float4 o = *(const float4*)&Cf[row * 260 + c * 4];
        *(float4*)((float*)Cout + coff + (long long)(bm + p * 64 + row) * N + bn + c * 4) = o;
      }
      __syncthreads();
    }
  }
#undef STAGE256
}

// ---------------------------------------------------------------------------
// Vision-direction attention + fused column sum-exp (fixed reference m=0).
// ---------------------------------------------------------------------------
__global__ __launch_bounds__(256, 3) void attn_fwd_v(
    const bf16* __restrict__ qv,   // [B*NV][2048], q = cols 0..1023 (scale folded in W)
    const bf16* __restrict__ kv,   // [B*NL][2048], k = cols 0..1023
    const bf16* __restrict__ vlT,  // [B*H][HD][NL]
    const int* __restrict__ mask,  // [B][NL]
    bf16* __restrict__ ovh,        // [B*NV][E]
    float* __restrict__ sfin) {    // [64 bh][256] column sum-exp (pre-zeroed)
  __shared__ short kp_lds[256 * 72];  // k tile (stride 72, mask in pad) -> P (stride 268) -> out (stride 72)
  __shared__ float stf[1024];         // [4 wave][256 col] partial column sums
  const int tid = threadIdx.x, wave = tid >> 6, lane = tid & 63;
  const int qt = blockIdx.x, bh = blockIdx.y;
  const int b = bh >> 4, h = bh & 15;
  const size_t qrow0 = (size_t)b * NVTOK + qt * 64;
  const size_t krow0 = (size_t)b * NLTOK;
  const int rl = lane & 15, lg = lane >> 4;

#pragma unroll
  for (int it = 0; it < 8; it++) {
    int vv = it * 256 + tid;
    int nl = vv >> 3, c = vv & 7;
    *(bf16x8*)&kp_lds[nl * 72 + c * 8] =
        *(const bf16x8*)((const short*)kv + (krow0 + nl) * 2048 + h * HD + c * 8);
  }
  kp_lds[tid * 72 + 64] = (short)(mask[b * NLTOK + tid] != 0);  // mask in row pads
  __syncthreads();  // bar1: k tile + mask visible

  floatx4 sacc[16];
#pragma unroll
  for (int ct = 0; ct < 16; ct++) sacc[ct] = (floatx4){0.f, 0.f, 0.f, 0.f};
  const short* qrow = (const short*)qv + (qrow0 + wave * 16 + rl) * 2048 + h * HD;
  bf16x8 a0 = *(const bf16x8*)(qrow + lg * 8);
  bf16x8 a1 = *(const bf16x8*)(qrow + 32 + lg * 8);
#pragma unroll
  for (int ct = 0; ct < 16; ct++) {
    bf16x8 b0 = *(const bf16x8*)&kp_lds[(ct * 16 + rl) * 72 + lg * 8];
    bf16x8 b1 = *(const bf16x8*)&kp_lds[(ct * 16 + rl) * 72 + 32 + lg * 8];
    sacc[ct] = MFMA(a0, b0, sacc[ct]);
    sacc[ct] = MFMA(a1, b1, sacc[ct]);
  }

  // Preload this wave's 8 vlT fragments (d-slice wave*16..) — latency hides
  // under the softmax below.
  const short* vbase = (const short*)vlT + ((size_t)bh * 64 + wave * 16) * 256;
  bf16x8 vfr[8];
#pragma unroll
  for (int ks = 0; ks < 8; ks++)
    vfr[ks] = *(const bf16x8*)(vbase + (size_t)rl * 256 + ks * 32 + lg * 8);

  // pre-mask column sum-exp (reference 0) partials
#pragma unroll
  for (int ct = 0; ct < 16; ct++) {
    float s = __expf(sacc[ct][0]) + __expf(sacc[ct][1]) +
              __expf(sacc[ct][2]) + __expf(sacc[ct][3]);
    s += __shfl_xor(s, 16);
    s += __shfl_xor(s, 32);
    if (lane < 16) stf[wave * 256 + ct * 16 + lane] = s;
  }

  // mask bias (from k-row pads; intact until bar2)
  float mb[16];
#pragma unroll
  for (int ct = 0; ct < 16; ct++)
    mb[ct] = kp_lds[(ct * 16 + rl) * 72 + 64] ? 0.0f : -1e9f;

  // masked row softmax, in registers (rows = wave*16 + lg*4 + r, cols = ct*16 + rl)
  float rmax[4] = {-1e30f, -1e30f, -1e30f, -1e30f};
#pragma unroll
  for (int ct = 0; ct < 16; ct++)
#pragma unroll
    for (int r = 0; r < 4; r++) {
      sacc[ct][r] += mb[ct];
      rmax[r] = fmaxf(rmax[r], sacc[ct][r]);
    }
#pragma unroll
  for (int r = 0; r < 4; r++) {
    rmax[r] = fmaxf(rmax[r], __shfl_xor(rmax[r], 1));
    rmax[r] = fmaxf(rmax[r], __shfl_xor(rmax[r], 2));
    rmax[r] = fmaxf(rmax[r], __shfl_xor(rmax[r], 4));
    rmax[r] = fmaxf(rmax[r], __shfl_xor(rmax[r], 8));
  }
  float rsum[4] = {0.f, 0.f, 0.f, 0.f};
#pragma unroll
  for (int ct = 0; ct < 16; ct++)
#pragma unroll
    for (int r = 0; r < 4; r++) {
      sacc[ct][r] = __expf(sacc[ct][r] - rmax[r]);
      rsum[r] += sacc[ct][r];
    }
#pragma unroll
  for (int r = 0; r < 4; r++) {
    rsum[r] += __shfl_xor(rsum[r], 1);
    rsum[r] += __shfl_xor(rsum[r], 2);
    rsum[r] += __shfl_xor(rsum[r], 4);
    rsum[r] += __shfl_xor(rsum[r], 8);
    rsum[r] = 1.0f / fmaxf(rsum[r], 1e-20f);
  }
  __syncthreads();  // bar2: all k reads + stf writes done; P may overwrite k

  // merge 4 waves' column partials -> global atomic
  {
    float s = stf[tid] + stf[256 + tid] + stf[512 + tid] + stf[768 + tid];
    atomicAdd(&sfin[(size_t)bh * 256 + tid], s);
  }

  // write P (bf16), stride 268 shorts
#pragma unroll
  for (int ct = 0; ct < 16; ct++)
#pragma unroll
    for (int r = 0; r < 4; r++)
      kp_lds[(wave * 16 + lg * 4 + r) * 268 + ct * 16 + rl] = f2bs(sacc[ct][r] * rsum[r]);
  __syncthreads();  // bar3: P visible to all waves

  // PV: wave computes out[mt*16+..][wave*16 + rl] for all 4 m-tiles
  floatx4 oacc[4];
#pragma unroll
  for (int mt = 0; mt < 4; mt++) oacc[mt] = (floatx4){0.f, 0.f, 0.f, 0.f};
#pragma unroll
  for (int ks = 0; ks < 8; ks++) {
#pragma unroll
    for (int mt = 0; mt < 4; mt++) {
      bf16x8 af = *(const bf16x8*)&kp_lds[(mt * 16 + rl) * 268 + ks * 32 + lg * 8];
      oacc[mt] = MFMA(af, vfr[ks], oacc[mt]);
    }
  }
  __syncthreads();  // bar4: all PV reads of P done

  // stage out tile [64 q][64 d] (stride 72 shorts)
#pragma unroll
  for (int mt = 0; mt < 4; mt++)
#pragma unroll
    for (int r = 0; r < 4; r++)
      kp_lds[(mt * 16 + lg * 4 + r) * 72 + wave * 16 + rl] = f2bs(oacc[mt][r]);
  __syncthreads();  // bar5: out tile visible

  // coalesced store: 2 x b128 per thread
#pragma unroll
  for (int pass = 0; pass < 2; pass++) {
    int idx = pass * 256 + tid;
    int row = idx >> 3, c = idx & 7;
    bf16x8 o = *(const bf16x8*)&kp_lds[row * 72 + c * 8];
    *(bf16x8*)((short*)ovh + (qrow0 + row) * EMBED + h * HD + c * 8) = o;
  }
}

__global__ void zero_f32(float* __restrict__ p, int n) {
  int i = blockIdx.x * 256 + threadIdx.x;
  if (i < n) p[i] = 0.f;
}

// ---------------------------------------------------------------------------
// Language-direction attention: per block (512 q rows, one bh).
// ---------------------------------------------------------------------------
__global__ __launch_bounds__(256) void attn_fwd_l(
    const bf16* __restrict__ qv,  // [B*NV][2048], q cols 0..1023, val_v cols 1024..2047
    const bf16* __restrict__ kv,  // [B*NL][2048], k = cols 0..1023
    const float* __restrict__ sf, // [64 bh][256] column sum-exp
    float* __restrict__ olacc) {  // [B*NL][E] fp32, pre-zeroed
  __shared__ short k_lds[256 * 72];
  __shared__ short PT[256 * 40];
  __shared__ short vvT[64 * 40];
  __shared__ float sl[256];
  const int tid = threadIdx.x, wave = tid >> 6, lane = tid & 63;
  const int chunk = blockIdx.x, bh = blockIdx.y;
  const int b = bh >> 4, h = bh & 15;
  const size_t krow0 = (size_t)b * NLTOK;
  const size_t qbase = (size_t)b * NVTOK + chunk * 512;
  const int rl = lane & 15, lg = lane >> 4;

#pragma unroll
  for (int it = 0; it < 8; it++) {
    int vvi = it * 256 + tid;
    int nl = vvi >> 3, c = vvi & 7;
    *(bf16x8*)&k_lds[nl * 72 + c * 8] =
        *(const bf16x8*)((const short*)kv + (krow0 + nl) * 2048 + h * HD + c * 8);
  }
  sl[tid] = 1.0f / fmaxf(sf[(size_t)bh * 256 + tid], 1e-20f);
  __syncthreads();

  floatx4 acc[4][4];
#pragma unroll
  for (int rt = 0; rt < 4; rt++)
#pragma unroll
    for (int dt = 0; dt < 4; dt++) acc[rt][dt] = (floatx4){0.f, 0.f, 0.f, 0.f};

  const int qrt = wave & 1, ctb = (wave >> 1) * 8;
  for (int qs = 0; qs < 16; qs++) {
    const short* qrow = (const short*)qv + (qbase + qs * 32 + qrt * 16 + rl) * 2048 + h * HD;
    bf16x8 a0 = *(const bf16x8*)(qrow + lg * 8);
    bf16x8 a1 = *(const bf16x8*)(qrow + 32 + lg * 8);
    floatx4 s8[8];
#pragma unroll
    for (int i = 0; i < 8; i++) {
      int ct = ctb + i;
      bf16x8 b0 = *(const bf16x8*)&k_lds[(ct * 16 + rl) * 72 + lg * 8];
      bf16x8 b1 = *(const bf16x8*)&k_lds[(ct * 16 + rl) * 72 + 32 + lg * 8];
      floatx4 s = (floatx4){0.f, 0.f, 0.f, 0.f};
      s = MFMA(a0, b0, s);
      s = MFMA(a1, b1, s);
      s8[i] = s;
    }
    __syncthreads();  // previous iteration's PT/vvT reads complete
#pragma unroll
    for (int i = 0; i < 8; i++) {
      int col = (ctb + i) * 16 + rl;
      float linv = sl[col];
#pragma unroll
      for (int r = 0; r < 4; r++)
        PT[col * 40 + qrt * 16 + lg * 4 + r] = f2bs(__expf(s8[i][r]) * linv);
    }
    {
      int qq = tid >> 3, c = tid & 7;
      bf16x8 vvv = *(const bf16x8*)((const short*)qv +
                                    (qbase + qs * 32 + qq) * 2048 + 1024 + h * HD + c * 8);
      const short* vp = (const short*)&vvv;
#pragma unroll
      for (int j = 0; j < 8; j++) vvT[(c * 8 + j) * 40 + qq] = vp[j];
    }
    __syncthreads();
#pragma unroll
    for (int rt = 0; rt < 4; rt++) {
      bf16x8 af = *(const bf16x8*)&PT[(wave * 64 + rt * 16 + rl) * 40 + lg * 8];
#pragma unroll
      for (int dt = 0; dt < 4; dt++) {
        bf16x8 bfr = *(const bf16x8*)&vvT[(dt * 16 + rl) * 40 + lg * 8];
        acc[rt][dt] = MFMA(af, bfr, acc[rt][dt]);
      }
    }
  }
#pragma unroll
  for (int rt = 0; rt < 4; rt++)
#pragma unroll
    for (int dt = 0; dt < 4; dt++)
#pragma unroll
      for (int r = 0; r < 4; r++) {
        int nl = wave * 64 + rt * 16 + lg * 4 + r;
        int d = dt * 16 + rl;
        atomicAdd(&olacc[((size_t)b * NLTOK + nl) * EMBED + h * HD + d], acc[rt][dt][r]);
      }
}

__global__ void finalize_out_l(const float* __restrict__ olacc, bf16* __restrict__ olh) {
  int i = blockIdx.x * 256 + threadIdx.x;
  if (i < 1024 * 1024) olh[i] = __float2bfloat16(olacc[i]);
}

// ---------------------------------------------------------------------------
extern "C" void kernel_launch(void* const* d_in, const int* in_sizes, int n_in,
                              void* d_out, int out_size, void* d_ws, size_t ws_size,
                              hipStream_t stream) {
  (void)in_sizes; (void)n_in; (void)out_size; (void)ws_size;
  const void* v_raw = d_in[0];
  const void* l_raw = d_in[1];
  const int*  mask  = (const int*)d_in[2];
  const void* W_v2q = d_in[3];  const void* b_v2q = d_in[4];
  const void* W_l2k = d_in[5];  const void* b_l2k = d_in[6];
  const void* W_v2v = d_in[7];  const void* b_v2v = d_in[8];
  const void* W_l2v = d_in[9];  const void* b_l2v = d_in[10];
  const void* W_v2o = d_in[11]; const void* b_v2o = d_in[12];
  const void* W_l2o = d_in[13]; const void* b_l2o = d_in[14];

  static bool lds_attr_ok = false;
  if (!lds_attr_ok) {
    hipFuncSetAttribute((const void*)gemm256_nt,
                        hipFuncAttributeMaxDynamicSharedMemorySize, 131072);
    lds_attr_ok = true;
  }

  char* ws = (char*)d_ws;
  size_t off = 0;
  auto alloc = [&](size_t bytes) -> void* {
    void* p = ws + off;
    off += (bytes + 255) & ~(size_t)255;
    return p;
  };
  int*  flag   = (int*)alloc(256);
  bf16* vb     = (bf16*)alloc((size_t)16777216 * 2);  // later aliased by ovh
  bf16* lb     = (bf16*)alloc((size_t)786432 * 2);
  bf16* b_qv   = (bf16*)alloc(4096);   // [2048] = bq | bvv (bq pre-scaled)
  bf16* b_kvl  = (bf16*)alloc(4096);   // [2048] = bk | bvl
  bf16* bov    = (bf16*)alloc(2048);
  bf16* bol    = (bf16*)alloc(1536);
  bf16* Wqv    = (bf16*)alloc((size_t)2048 * 1024 * 2);  // [2048][1024] v2q(scaled)|v2v
  bf16* Wkvl   = (bf16*)alloc((size_t)2048 * 768 * 2);   // [2048][768]  l2k|l2v
  bf16* Wt_v2o = (bf16*)alloc((size_t)1024 * 1024 * 2);
  bf16* Wt_l2o = (bf16*)alloc((size_t)768 * 1024 * 2);
  bf16* qvb    = (bf16*)alloc((size_t)16384 * 2048 * 2); // merged q|val_v
  bf16* kvb    = (bf16*)alloc((size_t)1024 * 2048 * 2);  // merged k|val_l
  bf16* vlT    = (bf16*)alloc((size_t)64 * 64 * 256 * 2);
  float* sfin  = (float*)alloc((size_t)64 * 256 * 4);
  float* olacc = (float*)alloc((size_t)1024 * 1024 * 4);
  bf16* olh    = (bf16*)alloc((size_t)1024 * 1024 * 2);
  bf16* ovh    = vb;  // vb dead after v-projection

  detect_dtype<<<1, 256, 0, stream>>>((const unsigned*)v_raw, flag);

  convert_to_bf16_v4<<<16384, 256, 0, stream>>>(v_raw, vb, 4194304, flag);
  convert_to_bf16_v4<<<768, 256, 0, stream>>>(l_raw, lb, 196608, flag);

  BArgs ba;
  ba.src[0] = b_v2q; ba.dst[0] = b_qv;         ba.n[0] = 1024; ba.scale[0] = QSCALE;
  ba.src[1] = b_l2k; ba.dst[1] = b_kvl;        ba.n[1] = 1024; ba.scale[1] = 1.0f;
  ba.src[2] = b_v2v; ba.dst[2] = b_qv + 1024;  ba.n[2] = 1024; ba.scale[2] = 1.0f;
  ba.src[3] = b_l2v; ba.dst[3] = b_kvl + 1024; ba.n[3] = 1024; ba.scale[3] = 1.0f;
  ba.src[4] = b_v2o; ba.dst[4] = bov;          ba.n[4] = 1024; ba.scale[4] = 1.0f;
  ba.src[5] = b_l2o; ba.dst[5] = bol;          ba.n[5] = 768;  ba.scale[5] = 1.0f;
  convert_bias_all<<<dim3(4, 6), 256, 0, stream>>>(ba, flag);

  WTArgs wa;
  wa.src[0] = W_v2q; wa.dst[0] = Wqv;                     wa.R[0] = 1024; wa.C[0] = 1024; wa.scale[0] = QSCALE;
  wa.src[1] = W_l2k; wa.dst[1] = Wkvl;                    wa.R[1] = 768;  wa.C[1] = 1024; wa.scale[1] = 1.0f;
  wa.src[2] = W_v2v; wa.dst[2] = Wqv + (size_t)1024*1024; wa.R[2] = 1024; wa.C[2] = 1024; wa.scale[2] = 1.0f;
  wa.src[3] = W_l2v; wa.dst[3] = Wkvl + (size_t)1024*768; wa.R[3] = 768;  wa.C[3] = 1024; wa.scale[3] = 1.0f;
  wa.src[4] = W_v2o; wa.dst[4] = Wt_v2o;                  wa.R[4] = 1024; wa.C[4] = 1024; wa.scale[4] = 1.0f;
  wa.src[5] = W_l2o; wa.dst[5] = Wt_l2o;                  wa.R[5] = 1024; wa.C[5] = 768;  wa.scale[5] = 1.0f;
  convert_transpose_all<<<dim3(1024, 6), 256, 0, stream>>>(wa, flag);

  // zero accumulators early (independent of everything above)
  zero_f32<<<64, 256, 0, stream>>>(sfin, 64 * 256);
  zero_f32<<<4096, 256, 0, stream>>>(olacc, 1024 * 1024);

  const int* bf16out = flag + 1;  // constant 0
  // merged projections: [v] -> q|val_v (N=2048, 256^2 deep-pipe), [l] -> k|val_l
  gemm256_nt<<<512, 512, 131072, stream>>>(vb, Wqv, b_qv, qvb, 0, 16384, 2048, 1024, 1.0f, bf16out);
  gemm_nt<<<dim3(8, 16), 256, 0, stream>>>(lb, Wkvl, b_kvl, kvb, 0, 1024, 2048, 768, 1.0f, bf16out);
  transpose_vl_heads<<<dim3(4, 64), 256, 0, stream>>>(kvb, vlT);

  // attention (vb is dead now; ovh aliases it)
  attn_fwd_v<<<dim3(64, 64), 256, 0, stream>>>(qvb, kvb, vlT, mask, ovh, sfin);
  attn_fwd_l<<<dim3(8, 64), 256, 0, stream>>>(qvb, kvb, sfin, olacc);
  finalize_out_l<<<4096, 256, 0, stream>>>(olacc, olh);

  // output projections straight into d_out (dtype per flag)
  gemm256_nt<<<256, 512, 131072, stream>>>(ovh, Wt_v2o, bov, d_out, 0, 16384, 1024, 1024, 1.0f, flag);
  gemm_nt<<<dim3(8, 6), 256, 0, stream>>>(olh, Wt_l2o, bol, d_out, 16777216LL, 1024, 768, 1024, 1.0f, flag);
}

// Round 6
// 486.956 us; speedup vs baseline: 1.2978x; 1.2978x over previous
//
#include <hip/hip_runtime.h>
#include <hip/hip_bf16.h>

#define EMBED 1024
#define HEADS 16
#define HD 64
#define NVTOK 4096
#define NLTOK 256
#define BATCH 4
#define QSCALE 0.25f   // HEADS**-0.5

typedef __hip_bfloat16 bf16;
typedef __attribute__((ext_vector_type(8))) short bf16x8;
typedef __attribute__((ext_vector_type(4))) float floatx4;

#define MFMA(a, b, c) __builtin_amdgcn_mfma_f32_16x16x32_bf16((a), (b), (c), 0, 0, 0)

static __device__ __forceinline__ short f2bs(float x) {
  bf16 h = __float2bfloat16(x);
  return *reinterpret_cast<short*>(&h);
}
static __device__ __forceinline__ float b2f(bf16 x) { return __bfloat162float(x); }

// Async global->LDS, 16B per lane. LDS dest = wave-uniform base + lane*16.
typedef const __attribute__((address_space(1))) char ga_char;
typedef __attribute__((address_space(3))) char ls_char;
static __device__ __forceinline__ void load_lds16(const void* g, void* lds) {
  __builtin_amdgcn_global_load_lds((ga_char*)g, (ls_char*)(unsigned)(size_t)(lds), 16, 0, 0);
}

// ---------------------------------------------------------------------------
// Input dtype detector (fp32 vs bf16 packed). flag[0]=1 => fp32.
// ---------------------------------------------------------------------------
__global__ void detect_dtype(const unsigned* __restrict__ v, int* __restrict__ flag) {
  __shared__ int cnt;
  if (threadIdx.x == 0) cnt = 0;
  __syncthreads();
  unsigned u = v[threadIdx.x];
  int mid = (int)((u >> 7) & 0xFF);
  if (mid >= 110 && mid <= 140) atomicAdd(&cnt, 1);
  __syncthreads();
  if (threadIdx.x == 0) {
    flag[0] = (cnt < 192) ? 1 : 0;
    flag[1] = 0;
  }
}

// ---------------------------------------------------------------------------
// Vectorized input convert (4 elements/thread). n4 = n/4.
// ---------------------------------------------------------------------------
__global__ void convert_to_bf16_v4(const void* __restrict__ src, bf16* __restrict__ dst,
                                   int n4, const int* __restrict__ flag) {
  int i = blockIdx.x * 256 + threadIdx.x;
  if (i >= n4) return;
  short4 o;
  if (flag[0]) {
    float4 f = ((const float4*)src)[i];
    o.x = f2bs(f.x); o.y = f2bs(f.y); o.z = f2bs(f.z); o.w = f2bs(f.w);
  } else {
    o = ((const short4*)src)[i];
  }
  ((short4*)dst)[i] = o;
}

// Batched weight convert+transpose (+ per-weight scale): src [R][C] -> dst [C][R].
struct WTArgs {
  const void* src[6];
  bf16* dst[6];
  int R[6];
  int C[6];
  float scale[6];
};
__global__ __launch_bounds__(256) void convert_transpose_all(WTArgs a, const int* __restrict__ flag) {
  __shared__ float tile[32][33];
  const int z = blockIdx.y;
  const int R = a.R[z], C = a.C[z];
  const float sc = a.scale[z];
  const int tpc = C >> 5;
  const int nt = (R >> 5) * tpc;
  const int t = blockIdx.x;
  if (t >= nt) return;
  const int r0 = (t / tpc) << 5, c0 = (t % tpc) << 5;
  {
    const int row = threadIdx.x >> 3, cg = (threadIdx.x & 7) << 2;
    if (flag[0]) {
      float4 f = *(const float4*)((const float*)a.src[z] + (size_t)(r0 + row) * C + c0 + cg);
      tile[row][cg] = f.x * sc; tile[row][cg + 1] = f.y * sc;
      tile[row][cg + 2] = f.z * sc; tile[row][cg + 3] = f.w * sc;
    } else {
      short4 f = *(const short4*)((const short*)a.src[z] + (size_t)(r0 + row) * C + c0 + cg);
      tile[row][cg]     = b2f(*(const bf16*)&f.x) * sc;
      tile[row][cg + 1] = b2f(*(const bf16*)&f.y) * sc;
      tile[row][cg + 2] = b2f(*(const bf16*)&f.z) * sc;
      tile[row][cg + 3] = b2f(*(const bf16*)&f.w) * sc;
    }
  }
  __syncthreads();
  {
    const int col = threadIdx.x >> 3, rg = (threadIdx.x & 7) << 2;
    short4 o;
    o.x = f2bs(tile[rg + 0][col]);
    o.y = f2bs(tile[rg + 1][col]);
    o.z = f2bs(tile[rg + 2][col]);
    o.w = f2bs(tile[rg + 3][col]);
    *(short4*)((short*)a.dst[z] + (size_t)(c0 + col) * R + r0 + rg) = o;
  }
}

// Batched bias convert (+ scale).
struct BArgs {
  const void* src[6];
  bf16* dst[6];
  int n[6];
  float scale[6];
};
__global__ void convert_bias_all(BArgs a, const int* __restrict__ flag) {
  int z = blockIdx.y;
  int i = blockIdx.x * 256 + threadIdx.x;
  if (i >= a.n[z]) return;
  float x = flag[0] ? ((const float*)a.src[z])[i] : b2f(((const bf16*)a.src[z])[i]);
  a.dst[z][i] = __float2bfloat16(x * a.scale[z]);
}

// ---------------------------------------------------------------------------
// val_l per-head transpose: vl = kv[:, 1024:2048] -> vlT [B*H][HD][NL]
// ---------------------------------------------------------------------------
__global__ __launch_bounds__(256) void transpose_vl_heads(const bf16* __restrict__ kv,
                                                          bf16* __restrict__ vlT) {
  __shared__ short t[64][72];
  const int bh = blockIdx.y, b = bh >> 4, h = bh & 15;
  const int nl0 = blockIdx.x << 6;
  const int tid = threadIdx.x;
  {
    const int nl = tid >> 2, dg = (tid & 3) << 4;
    const short* s = (const short*)kv + ((size_t)b * NLTOK + nl0 + nl) * 2048 + 1024 + h * HD + dg;
    *(bf16x8*)&t[nl][dg]     = *(const bf16x8*)s;
    *(bf16x8*)&t[nl][dg + 8] = *(const bf16x8*)(s + 8);
  }
  __syncthreads();
  {
    const int d = tid >> 2, ng = (tid & 3) << 4;
    short* o = (short*)vlT + ((size_t)bh * HD + d) * NLTOK + nl0 + ng;
    short tmp[16];
#pragma unroll
    for (int j = 0; j < 16; j++) tmp[j] = t[ng + j][d];
    *(bf16x8*)o       = *(bf16x8*)&tmp[0];
    *(bf16x8*)(o + 8) = *(bf16x8*)&tmp[8];
  }
}

// ---------------------------------------------------------------------------
// Small/medium NT GEMM (m97 128x128 pattern, BK=64, LDS-staged epilogue).
// Used for the small l-side GEMMs.
// ---------------------------------------------------------------------------
__global__ __launch_bounds__(256) void gemm_nt(
    const bf16* __restrict__ A, const bf16* __restrict__ Bt,
    const bf16* __restrict__ bias, void* __restrict__ Cout, long long coff,
    int M, int N, int K, float alpha, const int* __restrict__ outf) {
  __shared__ short lds_all[16896];
  short* As = lds_all;
  short* Bs = lds_all + 8192;
  const int f32o = outf[0];
  const int tid = threadIdx.x;
  const int wave = tid >> 6, lane = tid & 63;
  const int bm = blockIdx.x * 128, bn = blockIdx.y * 128;
  const int wr = (wave & 1) * 64, wc = (wave >> 1) * 64;
  const int rl = lane & 15, kg = (lane >> 4) * 8;

  const int srow = wave * 16 + (lane >> 2);
  const int scol = (lane & 3) * 8;
  const short* Ag = (const short*)A + (size_t)(bm + srow) * K + scol;
  const short* Bg = (const short*)Bt + (size_t)(bn + srow) * K + scol;
  short* As0l = &As[wave * 512];
  short* As1l = &As[2048 + wave * 512];
  short* As0h = &As[4096 + wave * 512];
  short* As1h = &As[6144 + wave * 512];
  short* Bs0l = &Bs[wave * 512];
  short* Bs1l = &Bs[2048 + wave * 512];
  short* Bs0h = &Bs[4096 + wave * 512];
  short* Bs1h = &Bs[6144 + wave * 512];
  const size_t rstep = (size_t)64 * K;

  floatx4 acc[4][4];
#pragma unroll
  for (int i = 0; i < 4; i++)
#pragma unroll
    for (int j = 0; j < 4; j++) acc[i][j] = (floatx4){0.f, 0.f, 0.f, 0.f};

  for (int k0 = 0; k0 < K; k0 += 64) {
    __syncthreads();
    load_lds16(Ag + k0, As0l);
    load_lds16(Ag + rstep + k0, As1l);
    load_lds16(Ag + k0 + 32, As0h);
    load_lds16(Ag + rstep + k0 + 32, As1h);
    load_lds16(Bg + k0, Bs0l);
    load_lds16(Bg + rstep + k0, Bs1l);
    load_lds16(Bg + k0 + 32, Bs0h);
    load_lds16(Bg + rstep + k0 + 32, Bs1h);
    __syncthreads();
#pragma unroll
    for (int half = 0; half < 2; half++) {
      const short* Ah = &As[half * 4096];
      const short* Bh = &Bs[half * 4096];
      bf16x8 af[4], bfr[4];
#pragma unroll
      for (int i = 0; i < 4; i++) af[i]  = *(const bf16x8*)&Ah[(wr + i * 16 + rl) * 32 + kg];
#pragma unroll
      for (int j = 0; j < 4; j++) bfr[j] = *(const bf16x8*)&Bh[(wc + j * 16 + rl) * 32 + kg];
#pragma unroll
      for (int i = 0; i < 4; i++)
#pragma unroll
        for (int j = 0; j < 4; j++) acc[i][j] = MFMA(af[i], bfr[j], acc[i][j]);
    }
  }

  const int rg = (lane >> 4) * 4;
  __syncthreads();  // all K-loop LDS reads done; reuse lds_all for C staging

  if (!f32o) {
#pragma unroll
    for (int j = 0; j < 4; j++) {
      float bv = b2f(bias[bn + wc + j * 16 + rl]);
#pragma unroll
      for (int i = 0; i < 4; i++)
#pragma unroll
        for (int r = 0; r < 4; r++)
          lds_all[(wr + i * 16 + rg + r) * 132 + wc + j * 16 + rl] =
              f2bs((acc[i][j][r] + bv) * alpha);
    }
    __syncthreads();
#pragma unroll
    for (int it = 0; it < 8; it++) {
      int idx = it * 256 + tid;
      int row = idx >> 4, c = idx & 15;
      bf16x8 o = *(const bf16x8*)&lds_all[row * 132 + c * 8];
      *(bf16x8*)((short*)Cout + coff + (long long)(bm + row) * N + bn + c * 8) = o;
    }
  } else {
    float* Cf = (float*)lds_all;
#pragma unroll
    for (int p = 0; p < 2; p++) {
      if ((wave & 1) == p) {
#pragma unroll
        for (int j = 0; j < 4; j++) {
          float bv = b2f(bias[bn + wc + j * 16 + rl]);
#pragma unroll
          for (int i = 0; i < 4; i++)
#pragma unroll
            for (int r = 0; r < 4; r++)
              Cf[(i * 16 + rg + r) * 132 + wc + j * 16 + rl] = (acc[i][j][r] + bv) * alpha;
        }
      }
      __syncthreads();
#pragma unroll
      for (int it = 0; it < 8; it++) {
        int idx = it * 256 + tid;
        int row = idx >> 5, c = idx & 31;
        float4 o = *(const float4*)&Cf[row * 132 + c * 4];
        *(float4*)((float*)Cout + coff + (long long)(bm + p * 64 + row) * N + bn + c * 4) = o;
      }
      if (p == 0) __syncthreads();
    }
  }
}

// ---------------------------------------------------------------------------
// Big NT GEMM v3: 256x128 tile, BK=64, 512 threads (8 waves = 4M x 2N),
// per-wave output 64x64 -> acc[4][4] = 64 regs (R4's 128-reg acc was the
// spill cause; R5's asm-AGPR fix broke MFMA hazard insertion -> intrinsics
// only here). Deep pipeline kept from R4 (correctness-verified): counted
// vmcnt(6) -- never 0 in the loop -- double-buffered 96KiB LDS; per K-tile
// 2 phases of {ds_read; s_barrier; lgkmcnt(0)+sched_barrier; setprio(1);
// 16 MFMA; setprio(0); s_barrier}. Both-sides XOR swizzle (R4: 0 bank
// conflicts). XCD-bijective block swizzle. M%256==0, N%128==0, K%128==0.
// ---------------------------------------------------------------------------
#define VMCNT6() do { asm volatile("s_waitcnt vmcnt(6)" ::: "memory"); \
                      __builtin_amdgcn_sched_barrier(0); } while (0)
#define VMCNT0() do { asm volatile("s_waitcnt vmcnt(0)" ::: "memory"); \
                      __builtin_amdgcn_sched_barrier(0); } while (0)
#define P_PRE()  do { __builtin_amdgcn_s_barrier(); \
                      asm volatile("s_waitcnt lgkmcnt(0)" ::: "memory"); \
                      __builtin_amdgcn_sched_barrier(0); \
                      __builtin_amdgcn_s_setprio(1); } while (0)
#define P_POST() do { __builtin_amdgcn_s_setprio(0); \
                      __builtin_amdgcn_sched_barrier(0); \
                      __builtin_amdgcn_s_barrier(); } while (0)

static __device__ __forceinline__ void compute_tile256b(
    const short* __restrict__ Ab, const short* __restrict__ Bb,
    floatx4 (&acc)[4][4], int wm, int wn, int rl, int lg) {
  const int sw = rl & 7;
  bf16x8 a[4][2], b[2][2];
#define LDA(m, kk) (*(const bf16x8*)&Ab[(wm * 64 + (m) * 16 + rl) * 64 + ((((kk) * 4 + lg) ^ sw) * 8)])
#define LDB(n, kk) (*(const bf16x8*)&Bb[(wn * 64 + (n) * 16 + rl) * 64 + ((((kk) * 4 + lg) ^ sw) * 8)])
  // P1: a(m0-3), b(n0-1); MFMA (m0-3, n0-1)
#pragma unroll
  for (int m = 0; m < 4; m++) { a[m][0] = LDA(m, 0); a[m][1] = LDA(m, 1); }
#pragma unroll
  for (int n = 0; n < 2; n++) { b[n][0] = LDB(n, 0); b[n][1] = LDB(n, 1); }
  P_PRE();
#pragma unroll
  for (int m = 0; m < 4; m++)
#pragma unroll
    for (int n = 0; n < 2; n++) {
      acc[m][n] = MFMA(a[m][0], b[n][0], acc[m][n]);
      acc[m][n] = MFMA(a[m][1], b[n][1], acc[m][n]);
    }
  P_POST();
  // P2: b <- B(n2-3); MFMA (m0-3, n2-3)
#pragma unroll
  for (int n = 0; n < 2; n++) { b[n][0] = LDB(n + 2, 0); b[n][1] = LDB(n + 2, 1); }
  P_PRE();
#pragma unroll
  for (int m = 0; m < 4; m++)
#pragma unroll
    for (int n = 0; n < 2; n++) {
      acc[m][n + 2] = MFMA(a[m][0], b[n][0], acc[m][n + 2]);
      acc[m][n + 2] = MFMA(a[m][1], b[n][1], acc[m][n + 2]);
    }
  P_POST();
#undef LDA
#undef LDB
}

__global__ __launch_bounds__(512, 2) void gemm256b_nt(
    const bf16* __restrict__ A, const bf16* __restrict__ Bt,
    const bf16* __restrict__ bias, void* __restrict__ Cout, long long coff,
    int M, int N, int K, float alpha, const int* __restrict__ outf) {
  extern __shared__ short lds[];  // 98304 B = 49152 shorts
  short* A0 = lds;                // 16384 shorts (256x64)
  short* B0 = lds + 16384;        // 8192 shorts (128x64)
  short* A1 = lds + 24576;
  short* B1 = lds + 40960;
  const int f32o = outf[0];
  const int tid = threadIdx.x;
  const int wave = tid >> 6, lane = tid & 63;
  const int rl = lane & 15, lg = lane >> 4;
  const int wm = wave >> 1, wn = wave & 1;   // 4M x 2N wave grid

  // XCD-aware bijective swizzle (m204); mt-fastest within an XCD so each
  // XCD sweeps one B-panel column (L2-resident).
  const int nwg = gridDim.x;
  const int nMT = M >> 8;
  int orig = blockIdx.x;
  int qq = nwg >> 3, rr = nwg & 7, xcd = orig & 7, sidx = orig >> 3;
  int swz = (xcd < rr) ? (xcd * (qq + 1) + sidx)
                       : (rr * (qq + 1) + (xcd - rr) * qq + sidx);
  const int bm = (swz % nMT) * 256;
  const int bn = (swz / nMT) * 128;

  // staging: source col-group pre-swizzled (cg = (l&7) ^ (l>>3)) so
  // lds[row][slot] = global(row, slot ^ (row&7)); read side XORs the same.
  const int r8 = lane >> 3;
  const int cgs = (lane & 7) ^ r8;
  const short* ga = (const short*)A + (size_t)(bm + wave * 8 + r8) * K + cgs * 8;
  const short* gb = (const short*)Bt + (size_t)(bn + wave * 8 + r8) * K + cgs * 8;

#define STAGE(LA, LB, k0_) do {                                             \
    _Pragma("unroll")                                                       \
    for (int p = 0; p < 4; p++)                                             \
      load_lds16(ga + (size_t)(p * 64) * K + (k0_), (LA) + wave * 512 + p * 4096); \
    _Pragma("unroll")                                                       \
    for (int p = 0; p < 2; p++)                                             \
      load_lds16(gb + (size_t)(p * 64) * K + (k0_), (LB) + wave * 512 + p * 4096); \
  } while (0)

  floatx4 acc[4][4];
#pragma unroll
  for (int m = 0; m < 4; m++)
#pragma unroll
    for (int n = 0; n < 4; n++) acc[m][n] = (floatx4){0.f, 0.f, 0.f, 0.f};

  const int NT = K >> 6;  // even (K multiple of 128)
  STAGE(A0, B0, 0);
  STAGE(A1, B1, 64);
  int kt = 0;
  for (; kt + 2 < NT; kt += 2) {
    VMCNT6();  // tile kt landed (tile kt+1's 6 loads still in flight)
    __builtin_amdgcn_s_barrier();
    compute_tile256b(A0, B0, acc, wm, wn, rl, lg);
    STAGE(A0, B0, (kt + 2) * 64);  // safe: P2's trailing barrier = reads done
    VMCNT6();
    __builtin_amdgcn_s_barrier();
    compute_tile256b(A1, B1, acc, wm, wn, rl, lg);
    STAGE(A1, B1, (kt + 3) * 64);
  }
  VMCNT6();
  __builtin_amdgcn_s_barrier();
  compute_tile256b(A0, B0, acc, wm, wn, rl, lg);
  VMCNT0();
  __builtin_amdgcn_s_barrier();
  compute_tile256b(A1, B1, acc, wm, wn, rl, lg);
  __syncthreads();  // epilogue boundary; vmcnt already 0

  // Epilogue: stage C through LDS, fully coalesced 16B stores.
  if (!f32o) {
    // single pass: 256 x 128 bf16 tile, stride 136 shorts (69632 B < 98304)
#pragma unroll
    for (int n = 0; n < 4; n++) {
      float bv = b2f(bias[bn + wn * 64 + n * 16 + rl]);
#pragma unroll
      for (int m = 0; m < 4; m++)
#pragma unroll
        for (int r2 = 0; r2 < 4; r2++)
          lds[(wm * 64 + m * 16 + lg * 4 + r2) * 136 + wn * 64 + n * 16 + rl] =
              f2bs((acc[m][n][r2] + bv) * alpha);
    }
    __syncthreads();
#pragma unroll
    for (int it = 0; it < 8; it++) {
      int idx2 = it * 512 + tid;
      int row = idx2 >> 4, c = idx2 & 15;
      bf16x8 o = *(const bf16x8*)&lds[row * 136 + c * 8];
      *(bf16x8*)((short*)Cout + coff + (long long)(bm + row) * N + bn + c * 8) = o;
    }
  } else {
    // two 128-row passes, stride 132 floats (67584 B < 98304)
    float* Cf = (float*)lds;
#pragma unroll
    for (int pp = 0; pp < 2; pp++) {
      if ((wm >> 1) == pp) {
#pragma unroll
        for (int n = 0; n < 4; n++) {
          float bv = b2f(bias[bn + wn * 64 + n * 16 + rl]);
#pragma unroll
          for (int m = 0; m < 4; m++)
#pragma unroll
            for (int r2 = 0; r2 < 4; r2++)
              Cf[((wm & 1) * 64 + m * 16 + lg * 4 + r2) * 132 + wn * 64 + n * 16 + rl] =
                  (acc[m][n][r2] + bv) * alpha;
        }
      }
      __syncthreads();
#pragma unroll
      for (int it = 0; it < 8; it++) {
        int idx2 = it * 512 + tid;
        int row = idx2 >> 5, c = idx2 & 31;
        float4 o = *(const float4*)&Cf[row * 132 + c * 4];
        *(float4*)((float*)Cout + coff + (long long)(bm + pp * 128 + row) * N + bn + c * 4) = o;
      }
      __syncthreads();
    }
  }
#undef STAGE
}

// ---------------------------------------------------------------------------
// Vision-direction attention + fused column sum-exp (fixed reference m=0).
// ---------------------------------------------------------------------------
__global__ __launch_bounds__(256, 3) void attn_fwd_v(
    const bf16* __restrict__ qv,   // [B*NV][2048], q = cols 0..1023 (scale folded in W)
    const bf16* __restrict__ kv,   // [B*NL][2048], k = cols 0..1023
    const bf16* __restrict__ vlT,  // [B*H][HD][NL]
    const int* __restrict__ mask,  // [B][NL]
    bf16* __restrict__ ovh,        // [B*NV][E]
    float* __restrict__ sfin) {    // [64 bh][256] column sum-exp (pre-zeroed)
  __shared__ short kp_lds[256 * 72];  // k tile (stride 72, mask in pad) -> P (stride 268) -> out (stride 72)
  __shared__ float stf[1024];         // [4 wave][256 col] partial column sums
  const int tid = threadIdx.x, wave = tid >> 6, lane = tid & 63;
  const int qt = blockIdx.x, bh = blockIdx.y;
  const int b = bh >> 4, h = bh & 15;
  const size_t qrow0 = (size_t)b * NVTOK + qt * 64;
  const size_t krow0 = (size_t)b * NLTOK;
  const int rl = lane & 15, lg = lane >> 4;

#pragma unroll
  for (int it = 0; it < 8; it++) {
    int vv = it * 256 + tid;
    int nl = vv >> 3, c = vv & 7;
    *(bf16x8*)&kp_lds[nl * 72 + c * 8] =
        *(const bf16x8*)((const short*)kv + (krow0 + nl) * 2048 + h * HD + c * 8);
  }
  kp_lds[tid * 72 + 64] = (short)(mask[b * NLTOK + tid] != 0);  // mask in row pads
  __syncthreads();  // bar1: k tile + mask visible

  floatx4 sacc[16];
#pragma unroll
  for (int ct = 0; ct < 16; ct++) sacc[ct] = (floatx4){0.f, 0.f, 0.f, 0.f};
  const short* qrow = (const short*)qv + (qrow0 + wave * 16 + rl) * 2048 + h * HD;
  bf16x8 a0 = *(const bf16x8*)(qrow + lg * 8);
  bf16x8 a1 = *(const bf16x8*)(qrow + 32 + lg * 8);
#pragma unroll
  for (int ct = 0; ct < 16; ct++) {
    bf16x8 b0 = *(const bf16x8*)&kp_lds[(ct * 16 + rl) * 72 + lg * 8];
    bf16x8 b1 = *(const bf16x8*)&kp_lds[(ct * 16 + rl) * 72 + 32 + lg * 8];
    sacc[ct] = MFMA(a0, b0, sacc[ct]);
    sacc[ct] = MFMA(a1, b1, sacc[ct]);
  }

  // Preload this wave's 8 vlT fragments (d-slice wave*16..) — latency hides
  // under the softmax below.
  const short* vbase = (const short*)vlT + ((size_t)bh * 64 + wave * 16) * 256;
  bf16x8 vfr[8];
#pragma unroll
  for (int ks = 0; ks < 8; ks++)
    vfr[ks] = *(const bf16x8*)(vbase + (size_t)rl * 256 + ks * 32 + lg * 8);

  // pre-mask column sum-exp (reference 0) partials
#pragma unroll
  for (int ct = 0; ct < 16; ct++) {
    float s = __expf(sacc[ct][0]) + __expf(sacc[ct][1]) +
              __expf(sacc[ct][2]) + __expf(sacc[ct][3]);
    s += __shfl_xor(s, 16);
    s += __shfl_xor(s, 32);
    if (lane < 16) stf[wave * 256 + ct * 16 + lane] = s;
  }

  // mask bias (from k-row pads; intact until bar2)
  float mb[16];
#pragma unroll
  for (int ct = 0; ct < 16; ct++)
    mb[ct] = kp_lds[(ct * 16 + rl) * 72 + 64] ? 0.0f : -1e9f;

  // masked row softmax, in registers (rows = wave*16 + lg*4 + r, cols = ct*16 + rl)
  float rmax[4] = {-1e30f, -1e30f, -1e30f, -1e30f};
#pragma unroll
  for (int ct = 0; ct < 16; ct++)
#pragma unroll
    for (int r = 0; r < 4; r++) {
      sacc[ct][r] += mb[ct];
      rmax[r] = fmaxf(rmax[r], sacc[ct][r]);
    }
#pragma unroll
  for (int r = 0; r < 4; r++) {
    rmax[r] = fmaxf(rmax[r], __shfl_xor(rmax[r], 1));
    rmax[r] = fmaxf(rmax[r], __shfl_xor(rmax[r], 2));
    rmax[r] = fmaxf(rmax[r], __shfl_xor(rmax[r], 4));
    rmax[r] = fmaxf(rmax[r], __shfl_xor(rmax[r], 8));
  }
  float rsum[4] = {0.f, 0.f, 0.f, 0.f};
#pragma unroll
  for (int ct = 0; ct < 16; ct++)
#pragma unroll
    for (int r = 0; r < 4; r++) {
      sacc[ct][r] = __expf(sacc[ct][r] - rmax[r]);
      rsum[r] += sacc[ct][r];
    }
#pragma unroll
  for (int r = 0; r < 4; r++) {
    rsum[r] += __shfl_xor(rsum[r], 1);
    rsum[r] += __shfl_xor(rsum[r], 2);
    rsum[r] += __shfl_xor(rsum[r], 4);
    rsum[r] += __shfl_xor(rsum[r], 8);
    rsum[r] = 1.0f / fmaxf(rsum[r], 1e-20f);
  }
  __syncthreads();  // bar2: all k reads + stf writes done; P may overwrite k

  // merge 4 waves' column partials -> global atomic
  {
    float s = stf[tid] + stf[256 + tid] + stf[512 + tid] + stf[768 + tid];
    atomicAdd(&sfin[(size_t)bh * 256 + tid], s);
  }

  // write P (bf16), stride 268 shorts
#pragma unroll
  for (int ct = 0; ct < 16; ct++)
#pragma unroll
    for (int r = 0; r < 4; r++)
      kp_lds[(wave * 16 + lg * 4 + r) * 268 + ct * 16 + rl] = f2bs(sacc[ct][r] * rsum[r]);
  __syncthreads();  // bar3: P visible to all waves

  // PV: wave computes out[mt*16+..][wave*16 + rl] for all 4 m-tiles
  floatx4 oacc[4];
#pragma unroll
  for (int mt = 0; mt < 4; mt++) oacc[mt] = (floatx4){0.f, 0.f, 0.f, 0.f};
#pragma unroll
  for (int ks = 0; ks < 8; ks++) {
#pragma unroll
    for (int mt = 0; mt < 4; mt++) {
      bf16x8 af = *(const bf16x8*)&kp_lds[(mt * 16 + rl) * 268 + ks * 32 + lg * 8];
      oacc[mt] = MFMA(af, vfr[ks], oacc[mt]);
    }
  }
  __syncthreads();  // bar4: all PV reads of P done

  // stage out tile [64 q][64 d] (stride 72 shorts)
#pragma unroll
  for (int mt = 0; mt < 4; mt++)
#pragma unroll
    for (int r = 0; r < 4; r++)
      kp_lds[(mt * 16 + lg * 4 + r) * 72 + wave * 16 + rl] = f2bs(oacc[mt][r]);
  __syncthreads();  // bar5: out tile visible

  // coalesced store: 2 x b128 per thread
#pragma unroll
  for (int pass = 0; pass < 2; pass++) {
    int idx = pass * 256 + tid;
    int row = idx >> 3, c = idx & 7;
    bf16x8 o = *(const bf16x8*)&kp_lds[row * 72 + c * 8];
    *(bf16x8*)((short*)ovh + (qrow0 + row) * EMBED + h * HD + c * 8) = o;
  }
}

__global__ void zero_f32(float* __restrict__ p, int n) {
  int i = blockIdx.x * 256 + threadIdx.x;
  if (i < n) p[i] = 0.f;
}

// ---------------------------------------------------------------------------
// Language-direction attention: per block (512 q rows, one bh).
// ---------------------------------------------------------------------------
__global__ __launch_bounds__(256) void attn_fwd_l(
    const bf16* __restrict__ qv,  // [B*NV][2048], q cols 0..1023, val_v cols 1024..2047
    const bf16* __restrict__ kv,  // [B*NL][2048], k = cols 0..1023
    const float* __restrict__ sf, // [64 bh][256] column sum-exp
    float* __restrict__ olacc) {  // [B*NL][E] fp32, pre-zeroed
  __shared__ short k_lds[256 * 72];
  __shared__ short PT[256 * 40];
  __shared__ short vvT[64 * 40];
  __shared__ float sl[256];
  const int tid = threadIdx.x, wave = tid >> 6, lane = tid & 63;
  const int chunk = blockIdx.x, bh = blockIdx.y;
  const int b = bh >> 4, h = bh & 15;
  const size_t krow0 = (size_t)b * NLTOK;
  const size_t qbase = (size_t)b * NVTOK + chunk * 512;
  const int rl = lane & 15, lg = lane >> 4;

#pragma unroll
  for (int it = 0; it < 8; it++) {
    int vvi = it * 256 + tid;
    int nl = vvi >> 3, c = vvi & 7;
    *(bf16x8*)&k_lds[nl * 72 + c * 8] =
        *(const bf16x8*)((const short*)kv + (krow0 + nl) * 2048 + h * HD + c * 8);
  }
  sl[tid] = 1.0f / fmaxf(sf[(size_t)bh * 256 + tid], 1e-20f);
  __syncthreads();

  floatx4 acc[4][4];
#pragma unroll
  for (int rt = 0; rt < 4; rt++)
#pragma unroll
    for (int dt = 0; dt < 4; dt++) acc[rt][dt] = (floatx4){0.f, 0.f, 0.f, 0.f};

  const int qrt = wave & 1, ctb = (wave >> 1) * 8;
  for (int qs = 0; qs < 16; qs++) {
    const short* qrow = (const short*)qv + (qbase + qs * 32 + qrt * 16 + rl) * 2048 + h * HD;
    bf16x8 a0 = *(const bf16x8*)(qrow + lg * 8);
    bf16x8 a1 = *(const bf16x8*)(qrow + 32 + lg * 8);
    floatx4 s8[8];
#pragma unroll
    for (int i = 0; i < 8; i++) {
      int ct = ctb + i;
      bf16x8 b0 = *(const bf16x8*)&k_lds[(ct * 16 + rl) * 72 + lg * 8];
      bf16x8 b1 = *(const bf16x8*)&k_lds[(ct * 16 + rl) * 72 + 32 + lg * 8];
      floatx4 s = (floatx4){0.f, 0.f, 0.f, 0.f};
      s = MFMA(a0, b0, s);
      s = MFMA(a1, b1, s);
      s8[i] = s;
    }
    __syncthreads();  // previous iteration's PT/vvT reads complete
#pragma unroll
    for (int i = 0; i < 8; i++) {
      int col = (ctb + i) * 16 + rl;
      float linv = sl[col];
#pragma unroll
      for (int r = 0; r < 4; r++)
        PT[col * 40 + qrt * 16 + lg * 4 + r] = f2bs(__expf(s8[i][r]) * linv);
    }
    {
      int qq = tid >> 3, c = tid & 7;
      bf16x8 vvv = *(const bf16x8*)((const short*)qv +
                                    (qbase + qs * 32 + qq) * 2048 + 1024 + h * HD + c * 8);
      const short* vp = (const short*)&vvv;
#pragma unroll
      for (int j = 0; j < 8; j++) vvT[(c * 8 + j) * 40 + qq] = vp[j];
    }
    __syncthreads();
#pragma unroll
    for (int rt = 0; rt < 4; rt++) {
      bf16x8 af = *(const bf16x8*)&PT[(wave * 64 + rt * 16 + rl) * 40 + lg * 8];
#pragma unroll
      for (int dt = 0; dt < 4; dt++) {
        bf16x8 bfr = *(const bf16x8*)&vvT[(dt * 16 + rl) * 40 + lg * 8];
        acc[rt][dt] = MFMA(af, bfr, acc[rt][dt]);
      }
    }
  }
#pragma unroll
  for (int rt = 0; rt < 4; rt++)
#pragma unroll
    for (int dt = 0; dt < 4; dt++)
#pragma unroll
      for (int r = 0; r < 4; r++) {
        int nl = wave * 64 + rt * 16 + lg * 4 + r;
        int d = dt * 16 + rl;
        atomicAdd(&olacc[((size_t)b * NLTOK + nl) * EMBED + h * HD + d], acc[rt][dt][r]);
      }
}

__global__ void finalize_out_l(const float* __restrict__ olacc, bf16* __restrict__ olh) {
  int i = blockIdx.x * 256 + threadIdx.x;
  if (i < 1024 * 1024) olh[i] = __float2bfloat16(olacc[i]);
}

// ---------------------------------------------------------------------------
extern "C" void kernel_launch(void* const* d_in, const int* in_sizes, int n_in,
                              void* d_out, int out_size, void* d_ws, size_t ws_size,
                              hipStream_t stream) {
  (void)in_sizes; (void)n_in; (void)out_size; (void)ws_size;
  const void* v_raw = d_in[0];
  const void* l_raw = d_in[1];
  const int*  mask  = (const int*)d_in[2];
  const void* W_v2q = d_in[3];  const void* b_v2q = d_in[4];
  const void* W_l2k = d_in[5];  const void* b_l2k = d_in[6];
  const void* W_v2v = d_in[7];  const void* b_v2v = d_in[8];
  const void* W_l2v = d_in[9];  const void* b_l2v = d_in[10];
  const void* W_v2o = d_in[11]; const void* b_v2o = d_in[12];
  const void* W_l2o = d_in[13]; const void* b_l2o = d_in[14];

  static bool lds_attr_ok = false;
  if (!lds_attr_ok) {
    hipFuncSetAttribute((const void*)gemm256b_nt,
                        hipFuncAttributeMaxDynamicSharedMemorySize, 98304);
    lds_attr_ok = true;
  }

  char* ws = (char*)d_ws;
  size_t off = 0;
  auto alloc = [&](size_t bytes) -> void* {
    void* p = ws + off;
    off += (bytes + 255) & ~(size_t)255;
    return p;
  };
  int*  flag   = (int*)alloc(256);
  bf16* vb     = (bf16*)alloc((size_t)16777216 * 2);  // later aliased by ovh
  bf16* lb     = (bf16*)alloc((size_t)786432 * 2);
  bf16* b_qv   = (bf16*)alloc(4096);   // [2048] = bq | bvv (bq pre-scaled)
  bf16* b_kvl  = (bf16*)alloc(4096);   // [2048] = bk | bvl
  bf16* bov    = (bf16*)alloc(2048);
  bf16* bol    = (bf16*)alloc(1536);
  bf16* Wqv    = (bf16*)alloc((size_t)2048 * 1024 * 2);  // [2048][1024] v2q(scaled)|v2v
  bf16* Wkvl   = (bf16*)alloc((size_t)2048 * 768 * 2);   // [2048][768]  l2k|l2v
  bf16* Wt_v2o = (bf16*)alloc((size_t)1024 * 1024 * 2);
  bf16* Wt_l2o = (bf16*)alloc((size_t)768 * 1024 * 2);
  bf16* qvb    = (bf16*)alloc((size_t)16384 * 2048 * 2); // merged q|val_v
  bf16* kvb    = (bf16*)alloc((size_t)1024 * 2048 * 2);  // merged k|val_l
  bf16* vlT    = (bf16*)alloc((size_t)64 * 64 * 256 * 2);
  float* sfin  = (float*)alloc((size_t)64 * 256 * 4);      // contiguous with olacc
  float* olacc = (float*)alloc((size_t)1024 * 1024 * 4);
  bf16* olh    = (bf16*)alloc((size_t)1024 * 1024 * 2);
  bf16* ovh    = vb;  // vb dead after v-projection

  detect_dtype<<<1, 256, 0, stream>>>((const unsigned*)v_raw, flag);

  convert_to_bf16_v4<<<16384, 256, 0, stream>>>(v_raw, vb, 4194304, flag);
  convert_to_bf16_v4<<<768, 256, 0, stream>>>(l_raw, lb, 196608, flag);

  BArgs ba;
  ba.src[0] = b_v2q; ba.dst[0] = b_qv;         ba.n[0] = 1024; ba.scale[0] = QSCALE;
  ba.src[1] = b_l2k; ba.dst[1] = b_kvl;        ba.n[1] = 1024; ba.scale[1] = 1.0f;
  ba.src[2] = b_v2v; ba.dst[2] = b_qv + 1024;  ba.n[2] = 1024; ba.scale[2] = 1.0f;
  ba.src[3] = b_l2v; ba.dst[3] = b_kvl + 1024; ba.n[3] = 1024; ba.scale[3] = 1.0f;
  ba.src[4] = b_v2o; ba.dst[4] = bov;          ba.n[4] = 1024; ba.scale[4] = 1.0f;
  ba.src[5] = b_l2o; ba.dst[5] = bol;          ba.n[5] = 768;  ba.scale[5] = 1.0f;
  convert_bias_all<<<dim3(4, 6), 256, 0, stream>>>(ba, flag);

  WTArgs wa;
  wa.src[0] = W_v2q; wa.dst[0] = Wqv;                     wa.R[0] = 1024; wa.C[0] = 1024; wa.scale[0] = QSCALE;
  wa.src[1] = W_l2k; wa.dst[1] = Wkvl;                    wa.R[1] = 768;  wa.C[1] = 1024; wa.scale[1] = 1.0f;
  wa.src[2] = W_v2v; wa.dst[2] = Wqv + (size_t)1024*1024; wa.R[2] = 1024; wa.C[2] = 1024; wa.scale[2] = 1.0f;
  wa.src[3] = W_l2v; wa.dst[3] = Wkvl + (size_t)1024*768; wa.R[3] = 768;  wa.C[3] = 1024; wa.scale[3] = 1.0f;
  wa.src[4] = W_v2o; wa.dst[4] = Wt_v2o;                  wa.R[4] = 1024; wa.C[4] = 1024; wa.scale[4] = 1.0f;
  wa.src[5] = W_l2o; wa.dst[5] = Wt_l2o;                  wa.R[5] = 1024; wa.C[5] = 768;  wa.scale[5] = 1.0f;
  convert_transpose_all<<<dim3(1024, 6), 256, 0, stream>>>(wa, flag);

  // zero sfin+olacc in one pass (contiguous in ws)
  zero_f32<<<4161, 256, 0, stream>>>(sfin, 64 * 256 + 1024 * 1024);

  const int* bf16out = flag + 1;  // constant 0
  // merged projections: [v] -> q|val_v via 256x128 deep-pipe, [l] -> k|val_l
  gemm256b_nt<<<1024, 512, 98304, stream>>>(vb, Wqv, b_qv, qvb, 0, 16384, 2048, 1024, 1.0f, bf16out);
  gemm_nt<<<dim3(8, 16), 256, 0, stream>>>(lb, Wkvl, b_kvl, kvb, 0, 1024, 2048, 768, 1.0f, bf16out);
  transpose_vl_heads<<<dim3(4, 64), 256, 0, stream>>>(kvb, vlT);

  // attention (vb is dead now; ovh aliases it)
  attn_fwd_v<<<dim3(64, 64), 256, 0, stream>>>(qvb, kvb, vlT, mask, ovh, sfin);
  attn_fwd_l<<<dim3(8, 64), 256, 0, stream>>>(qvb, kvb, sfin, olacc);
  finalize_out_l<<<4096, 256, 0, stream>>>(olacc, olh);

  // output projections straight into d_out (dtype per flag)
  gemm256b_nt<<<512, 512, 98304, stream>>>(ovh, Wt_v2o, bov, d_out, 0, 16384, 1024, 1024, 1.0f, flag);
  gemm_nt<<<dim3(8, 6), 256, 0, stream>>>(olh, Wt_l2o, bol, d_out, 16777216LL, 1024, 768, 1024, 1.0f, flag);
}

// Round 7
// 475.187 us; speedup vs baseline: 1.3299x; 1.0248x over previous
//
#include <hip/hip_runtime.h>
#include <hip/hip_bf16.h>

#define EMBED 1024
#define HEADS 16
#define HD 64
#define NVTOK 4096
#define NLTOK 256
#define BATCH 4
#define QSCALE 0.25f   // HEADS**-0.5

typedef __hip_bfloat16 bf16;
typedef __attribute__((ext_vector_type(8))) short bf16x8;
typedef __attribute__((ext_vector_type(4))) float floatx4;

#define MFMA(a, b, c) __builtin_amdgcn_mfma_f32_16x16x32_bf16((a), (b), (c), 0, 0, 0)

static __device__ __forceinline__ short f2bs(float x) {
  bf16 h = __float2bfloat16(x);
  return *reinterpret_cast<short*>(&h);
}
static __device__ __forceinline__ float b2f(bf16 x) { return __bfloat162float(x); }

// Async global->LDS, 16B per lane. LDS dest = wave-uniform base + lane*16.
typedef const __attribute__((address_space(1))) char ga_char;
typedef __attribute__((address_space(3))) char ls_char;
static __device__ __forceinline__ void load_lds16(const void* g, void* lds) {
  __builtin_amdgcn_global_load_lds((ga_char*)g, (ls_char*)(unsigned)(size_t)(lds), 16, 0, 0);
}

// ---------------------------------------------------------------------------
// Input dtype detector (fp32 vs bf16 packed). flag[0]=1 => fp32.
// ---------------------------------------------------------------------------
__global__ void detect_dtype(const unsigned* __restrict__ v, int* __restrict__ flag) {
  __shared__ int cnt;
  if (threadIdx.x == 0) cnt = 0;
  __syncthreads();
  unsigned u = v[threadIdx.x];
  int mid = (int)((u >> 7) & 0xFF);
  if (mid >= 110 && mid <= 140) atomicAdd(&cnt, 1);
  __syncthreads();
  if (threadIdx.x == 0) {
    flag[0] = (cnt < 192) ? 1 : 0;
    flag[1] = 0;
  }
}

// ---------------------------------------------------------------------------
// Vectorized input convert (4 elements/thread). n4 = n/4.
// ---------------------------------------------------------------------------
__global__ void convert_to_bf16_v4(const void* __restrict__ src, bf16* __restrict__ dst,
                                   int n4, const int* __restrict__ flag) {
  int i = blockIdx.x * 256 + threadIdx.x;
  if (i >= n4) return;
  short4 o;
  if (flag[0]) {
    float4 f = ((const float4*)src)[i];
    o.x = f2bs(f.x); o.y = f2bs(f.y); o.z = f2bs(f.z); o.w = f2bs(f.w);
  } else {
    o = ((const short4*)src)[i];
  }
  ((short4*)dst)[i] = o;
}

// Batched weight convert+transpose (+ per-weight scale): src [R][C] -> dst [C][R].
struct WTArgs {
  const void* src[6];
  bf16* dst[6];
  int R[6];
  int C[6];
  float scale[6];
};
__global__ __launch_bounds__(256) void convert_transpose_all(WTArgs a, const int* __restrict__ flag) {
  __shared__ float tile[32][33];
  const int z = blockIdx.y;
  const int R = a.R[z], C = a.C[z];
  const float sc = a.scale[z];
  const int tpc = C >> 5;
  const int nt = (R >> 5) * tpc;
  const int t = blockIdx.x;
  if (t >= nt) return;
  const int r0 = (t / tpc) << 5, c0 = (t % tpc) << 5;
  {
    const int row = threadIdx.x >> 3, cg = (threadIdx.x & 7) << 2;
    if (flag[0]) {
      float4 f = *(const float4*)((const float*)a.src[z] + (size_t)(r0 + row) * C + c0 + cg);
      tile[row][cg] = f.x * sc; tile[row][cg + 1] = f.y * sc;
      tile[row][cg + 2] = f.z * sc; tile[row][cg + 3] = f.w * sc;
    } else {
      short4 f = *(const short4*)((const short*)a.src[z] + (size_t)(r0 + row) * C + c0 + cg);
      tile[row][cg]     = b2f(*(const bf16*)&f.x) * sc;
      tile[row][cg + 1] = b2f(*(const bf16*)&f.y) * sc;
      tile[row][cg + 2] = b2f(*(const bf16*)&f.z) * sc;
      tile[row][cg + 3] = b2f(*(const bf16*)&f.w) * sc;
    }
  }
  __syncthreads();
  {
    const int col = threadIdx.x >> 3, rg = (threadIdx.x & 7) << 2;
    short4 o;
    o.x = f2bs(tile[rg + 0][col]);
    o.y = f2bs(tile[rg + 1][col]);
    o.z = f2bs(tile[rg + 2][col]);
    o.w = f2bs(tile[rg + 3][col]);
    *(short4*)((short*)a.dst[z] + (size_t)(c0 + col) * R + r0 + rg) = o;
  }
}

// Batched bias convert (+ scale).
struct BArgs {
  const void* src[6];
  bf16* dst[6];
  int n[6];
  float scale[6];
};
__global__ void convert_bias_all(BArgs a, const int* __restrict__ flag) {
  int z = blockIdx.y;
  int i = blockIdx.x * 256 + threadIdx.x;
  if (i >= a.n[z]) return;
  float x = flag[0] ? ((const float*)a.src[z])[i] : b2f(((const bf16*)a.src[z])[i]);
  a.dst[z][i] = __float2bfloat16(x * a.scale[z]);
}

// ---------------------------------------------------------------------------
// val_l per-head transpose: vl = kv[:, 1024:2048] -> vlT [B*H][HD][NL]
// ---------------------------------------------------------------------------
__global__ __launch_bounds__(256) void transpose_vl_heads(const bf16* __restrict__ kv,
                                                          bf16* __restrict__ vlT) {
  __shared__ short t[64][72];
  const int bh = blockIdx.y, b = bh >> 4, h = bh & 15;
  const int nl0 = blockIdx.x << 6;
  const int tid = threadIdx.x;
  {
    const int nl = tid >> 2, dg = (tid & 3) << 4;
    const short* s = (const short*)kv + ((size_t)b * NLTOK + nl0 + nl) * 2048 + 1024 + h * HD + dg;
    *(bf16x8*)&t[nl][dg]     = *(const bf16x8*)s;
    *(bf16x8*)&t[nl][dg + 8] = *(const bf16x8*)(s + 8);
  }
  __syncthreads();
  {
    const int d = tid >> 2, ng = (tid & 3) << 4;
    short* o = (short*)vlT + ((size_t)bh * HD + d) * NLTOK + nl0 + ng;
    short tmp[16];
#pragma unroll
    for (int j = 0; j < 16; j++) tmp[j] = t[ng + j][d];
    *(bf16x8*)o       = *(bf16x8*)&tmp[0];
    *(bf16x8*)(o + 8) = *(bf16x8*)&tmp[8];
  }
}

// ---------------------------------------------------------------------------
// Small/medium NT GEMM (m97 128x128 pattern, BK=64, LDS-staged epilogue).
// Used for the small l-side GEMMs.
// ---------------------------------------------------------------------------
__global__ __launch_bounds__(256) void gemm_nt(
    const bf16* __restrict__ A, const bf16* __restrict__ Bt,
    const bf16* __restrict__ bias, void* __restrict__ Cout, long long coff,
    int M, int N, int K, float alpha, const int* __restrict__ outf) {
  __shared__ short lds_all[16896];
  short* As = lds_all;
  short* Bs = lds_all + 8192;
  const int f32o = outf[0];
  const int tid = threadIdx.x;
  const int wave = tid >> 6, lane = tid & 63;
  const int bm = blockIdx.x * 128, bn = blockIdx.y * 128;
  const int wr = (wave & 1) * 64, wc = (wave >> 1) * 64;
  const int rl = lane & 15, kg = (lane >> 4) * 8;

  const int srow = wave * 16 + (lane >> 2);
  const int scol = (lane & 3) * 8;
  const short* Ag = (const short*)A + (size_t)(bm + srow) * K + scol;
  const short* Bg = (const short*)Bt + (size_t)(bn + srow) * K + scol;
  short* As0l = &As[wave * 512];
  short* As1l = &As[2048 + wave * 512];
  short* As0h = &As[4096 + wave * 512];
  short* As1h = &As[6144 + wave * 512];
  short* Bs0l = &Bs[wave * 512];
  short* Bs1l = &Bs[2048 + wave * 512];
  short* Bs0h = &Bs[4096 + wave * 512];
  short* Bs1h = &Bs[6144 + wave * 512];
  const size_t rstep = (size_t)64 * K;

  floatx4 acc[4][4];
#pragma unroll
  for (int i = 0; i < 4; i++)
#pragma unroll
    for (int j = 0; j < 4; j++) acc[i][j] = (floatx4){0.f, 0.f, 0.f, 0.f};

  for (int k0 = 0; k0 < K; k0 += 64) {
    __syncthreads();
    load_lds16(Ag + k0, As0l);
    load_lds16(Ag + rstep + k0, As1l);
    load_lds16(Ag + k0 + 32, As0h);
    load_lds16(Ag + rstep + k0 + 32, As1h);
    load_lds16(Bg + k0, Bs0l);
    load_lds16(Bg + rstep + k0, Bs1l);
    load_lds16(Bg + k0 + 32, Bs0h);
    load_lds16(Bg + rstep + k0 + 32, Bs1h);
    __syncthreads();
#pragma unroll
    for (int half = 0; half < 2; half++) {
      const short* Ah = &As[half * 4096];
      const short* Bh = &Bs[half * 4096];
      bf16x8 af[4], bfr[4];
#pragma unroll
      for (int i = 0; i < 4; i++) af[i]  = *(const bf16x8*)&Ah[(wr + i * 16 + rl) * 32 + kg];
#pragma unroll
      for (int j = 0; j < 4; j++) bfr[j] = *(const bf16x8*)&Bh[(wc + j * 16 + rl) * 32 + kg];
#pragma unroll
      for (int i = 0; i < 4; i++)
#pragma unroll
        for (int j = 0; j < 4; j++) acc[i][j] = MFMA(af[i], bfr[j], acc[i][j]);
    }
  }

  const int rg = (lane >> 4) * 4;
  __syncthreads();  // all K-loop LDS reads done; reuse lds_all for C staging

  if (!f32o) {
#pragma unroll
    for (int j = 0; j < 4; j++) {
      float bv = b2f(bias[bn + wc + j * 16 + rl]);
#pragma unroll
      for (int i = 0; i < 4; i++)
#pragma unroll
        for (int r = 0; r < 4; r++)
          lds_all[(wr + i * 16 + rg + r) * 132 + wc + j * 16 + rl] =
              f2bs((acc[i][j][r] + bv) * alpha);
    }
    __syncthreads();
#pragma unroll
    for (int it = 0; it < 8; it++) {
      int idx = it * 256 + tid;
      int row = idx >> 4, c = idx & 15;
      bf16x8 o = *(const bf16x8*)&lds_all[row * 132 + c * 8];
      *(bf16x8*)((short*)Cout + coff + (long long)(bm + row) * N + bn + c * 8) = o;
    }
  } else {
    float* Cf = (float*)lds_all;
#pragma unroll
    for (int p = 0; p < 2; p++) {
      if ((wave & 1) == p) {
#pragma unroll
        for (int j = 0; j < 4; j++) {
          float bv = b2f(bias[bn + wc + j * 16 + rl]);
#pragma unroll
          for (int i = 0; i < 4; i++)
#pragma unroll
            for (int r = 0; r < 4; r++)
              Cf[(i * 16 + rg + r) * 132 + wc + j * 16 + rl] = (acc[i][j][r] + bv) * alpha;
        }
      }
      __syncthreads();
#pragma unroll
      for (int it = 0; it < 8; it++) {
        int idx = it * 256 + tid;
        int row = idx >> 5, c = idx & 31;
        float4 o = *(const float4*)&Cf[row * 132 + c * 4];
        *(float4*)((float*)Cout + coff + (long long)(bm + p * 64 + row) * N + bn + c * 4) = o;
      }
      if (p == 0) __syncthreads();
    }
  }
}

// ---------------------------------------------------------------------------
// Big NT GEMM v3: 256x128 tile, BK=64, 512 threads (8 waves = 4M x 2N),
// per-wave output 64x64 -> acc[4][4] = 64 regs. Deep pipeline: counted
// vmcnt(6) (never 0 in loop), double-buffered 96KiB LDS; per K-tile 2 phases
// of {ds_read; s_barrier; lgkmcnt(0)+sched_barrier; setprio(1); 16 MFMA;
// setprio(0); s_barrier}. Both-sides XOR swizzle (0 bank conflicts, R4/R6).
// R7 fix: bn-FASTEST block order within each XCD chunk. R6's bm-fastest made
// consecutive blocks walk all of A per B-column -> FETCH 266MB (A re-fetched
// ~8x, fetch-bound at 2.6TB/s). bn-fastest: 16 consecutive blocks share one
// 0.5MB A-panel (L2-resident) and sweep the 4MB weight (L3-resident).
// M%256==0, N%128==0, K%128==0.
// ---------------------------------------------------------------------------
#define VMCNT6() do { asm volatile("s_waitcnt vmcnt(6)" ::: "memory"); \
                      __builtin_amdgcn_sched_barrier(0); } while (0)
#define VMCNT0() do { asm volatile("s_waitcnt vmcnt(0)" ::: "memory"); \
                      __builtin_amdgcn_sched_barrier(0); } while (0)
#define P_PRE()  do { __builtin_amdgcn_s_barrier(); \
                      asm volatile("s_waitcnt lgkmcnt(0)" ::: "memory"); \
                      __builtin_amdgcn_sched_barrier(0); \
                      __builtin_amdgcn_s_setprio(1); } while (0)
#define P_POST() do { __builtin_amdgcn_s_setprio(0); \
                      __builtin_amdgcn_sched_barrier(0); \
                      __builtin_amdgcn_s_barrier(); } while (0)

static __device__ __forceinline__ void compute_tile256b(
    const short* __restrict__ Ab, const short* __restrict__ Bb,
    floatx4 (&acc)[4][4], int wm, int wn, int rl, int lg) {
  const int sw = rl & 7;
  bf16x8 a[4][2], b[2][2];
#define LDA(m, kk) (*(const bf16x8*)&Ab[(wm * 64 + (m) * 16 + rl) * 64 + ((((kk) * 4 + lg) ^ sw) * 8)])
#define LDB(n, kk) (*(const bf16x8*)&Bb[(wn * 64 + (n) * 16 + rl) * 64 + ((((kk) * 4 + lg) ^ sw) * 8)])
  // P1: a(m0-3), b(n0-1); MFMA (m0-3, n0-1)
#pragma unroll
  for (int m = 0; m < 4; m++) { a[m][0] = LDA(m, 0); a[m][1] = LDA(m, 1); }
#pragma unroll
  for (int n = 0; n < 2; n++) { b[n][0] = LDB(n, 0); b[n][1] = LDB(n, 1); }
  P_PRE();
#pragma unroll
  for (int m = 0; m < 4; m++)
#pragma unroll
    for (int n = 0; n < 2; n++) {
      acc[m][n] = MFMA(a[m][0], b[n][0], acc[m][n]);
      acc[m][n] = MFMA(a[m][1], b[n][1], acc[m][n]);
    }
  P_POST();
  // P2: b <- B(n2-3); MFMA (m0-3, n2-3)
#pragma unroll
  for (int n = 0; n < 2; n++) { b[n][0] = LDB(n + 2, 0); b[n][1] = LDB(n + 2, 1); }
  P_PRE();
#pragma unroll
  for (int m = 0; m < 4; m++)
#pragma unroll
    for (int n = 0; n < 2; n++) {
      acc[m][n + 2] = MFMA(a[m][0], b[n][0], acc[m][n + 2]);
      acc[m][n + 2] = MFMA(a[m][1], b[n][1], acc[m][n + 2]);
    }
  P_POST();
#undef LDA
#undef LDB
}

__global__ __launch_bounds__(512, 2) void gemm256b_nt(
    const bf16* __restrict__ A, const bf16* __restrict__ Bt,
    const bf16* __restrict__ bias, void* __restrict__ Cout, long long coff,
    int M, int N, int K, float alpha, const int* __restrict__ outf) {
  extern __shared__ short lds[];  // 98304 B = 49152 shorts
  short* A0 = lds;                // 16384 shorts (256x64)
  short* B0 = lds + 16384;        // 8192 shorts (128x64)
  short* A1 = lds + 24576;
  short* B1 = lds + 40960;
  const int f32o = outf[0];
  const int tid = threadIdx.x;
  const int wave = tid >> 6, lane = tid & 63;
  const int rl = lane & 15, lg = lane >> 4;
  const int wm = wave >> 1, wn = wave & 1;   // 4M x 2N wave grid

  // XCD-aware bijective swizzle (m204), bn-FASTEST within the chunk:
  // consecutive blocks share an A-panel (L2), sweep B (L3).
  const int nwg = gridDim.x;
  const int nNT = N >> 7;
  int orig = blockIdx.x;
  int qq = nwg >> 3, rr = nwg & 7, xcd = orig & 7, sidx = orig >> 3;
  int swz = (xcd < rr) ? (xcd * (qq + 1) + sidx)
                       : (rr * (qq + 1) + (xcd - rr) * qq + sidx);
  const int bm = (swz / nNT) * 256;
  const int bn = (swz % nNT) * 128;

  // staging: source col-group pre-swizzled (cg = (l&7) ^ (l>>3)) so
  // lds[row][slot] = global(row, slot ^ (row&7)); read side XORs the same.
  const int r8 = lane >> 3;
  const int cgs = (lane & 7) ^ r8;
  const short* ga = (const short*)A + (size_t)(bm + wave * 8 + r8) * K + cgs * 8;
  const short* gb = (const short*)Bt + (size_t)(bn + wave * 8 + r8) * K + cgs * 8;

#define STAGE(LA, LB, k0_) do {                                             \
    _Pragma("unroll")                                                       \
    for (int p = 0; p < 4; p++)                                             \
      load_lds16(ga + (size_t)(p * 64) * K + (k0_), (LA) + wave * 512 + p * 4096); \
    _Pragma("unroll")                                                       \
    for (int p = 0; p < 2; p++)                                             \
      load_lds16(gb + (size_t)(p * 64) * K + (k0_), (LB) + wave * 512 + p * 4096); \
  } while (0)

  floatx4 acc[4][4];
#pragma unroll
  for (int m = 0; m < 4; m++)
#pragma unroll
    for (int n = 0; n < 4; n++) acc[m][n] = (floatx4){0.f, 0.f, 0.f, 0.f};

  const int NT = K >> 6;  // even (K multiple of 128)
  STAGE(A0, B0, 0);
  STAGE(A1, B1, 64);
  int kt = 0;
  for (; kt + 2 < NT; kt += 2) {
    VMCNT6();  // tile kt landed (tile kt+1's 6 loads still in flight)
    __builtin_amdgcn_s_barrier();
    compute_tile256b(A0, B0, acc, wm, wn, rl, lg);
    STAGE(A0, B0, (kt + 2) * 64);  // safe: P2's trailing barrier = reads done
    VMCNT6();
    __builtin_amdgcn_s_barrier();
    compute_tile256b(A1, B1, acc, wm, wn, rl, lg);
    STAGE(A1, B1, (kt + 3) * 64);
  }
  VMCNT6();
  __builtin_amdgcn_s_barrier();
  compute_tile256b(A0, B0, acc, wm, wn, rl, lg);
  VMCNT0();
  __builtin_amdgcn_s_barrier();
  compute_tile256b(A1, B1, acc, wm, wn, rl, lg);
  __syncthreads();  // epilogue boundary; vmcnt already 0

  // Epilogue: stage C through LDS, fully coalesced 16B stores.
  if (!f32o) {
    // single pass: 256 x 128 bf16 tile, stride 136 shorts (69632 B < 98304)
#pragma unroll
    for (int n = 0; n < 4; n++) {
      float bv = b2f(bias[bn + wn * 64 + n * 16 + rl]);
#pragma unroll
      for (int m = 0; m < 4; m++)
#pragma unroll
        for (int r2 = 0; r2 < 4; r2++)
          lds[(wm * 64 + m * 16 + lg * 4 + r2) * 136 + wn * 64 + n * 16 + rl] =
              f2bs((acc[m][n][r2] + bv) * alpha);
    }
    __syncthreads();
#pragma unroll
    for (int it = 0; it < 8; it++) {
      int idx2 = it * 512 + tid;
      int row = idx2 >> 4, c = idx2 & 15;
      bf16x8 o = *(const bf16x8*)&lds[row * 136 + c * 8];
      *(bf16x8*)((short*)Cout + coff + (long long)(bm + row) * N + bn + c * 8) = o;
    }
  } else {
    // two 128-row passes, stride 132 floats (67584 B < 98304)
    float* Cf = (float*)lds;
#pragma unroll
    for (int pp = 0; pp < 2; pp++) {
      if ((wm >> 1) == pp) {
#pragma unroll
        for (int n = 0; n < 4; n++) {
          float bv = b2f(bias[bn + wn * 64 + n * 16 + rl]);
#pragma unroll
          for (int m = 0; m < 4; m++)
#pragma unroll
            for (int r2 = 0; r2 < 4; r2++)
              Cf[((wm & 1) * 64 + m * 16 + lg * 4 + r2) * 132 + wn * 64 + n * 16 + rl] =
                  (acc[m][n][r2] + bv) * alpha;
        }
      }
      __syncthreads();
#pragma unroll
      for (int it = 0; it < 8; it++) {
        int idx2 = it * 512 + tid;
        int row = idx2 >> 5, c = idx2 & 31;
        float4 o = *(const float4*)&Cf[row * 132 + c * 4];
        *(float4*)((float*)Cout + coff + (long long)(bm + pp * 128 + row) * N + bn + c * 4) = o;
      }
      __syncthreads();
    }
  }
#undef STAGE
}

// ---------------------------------------------------------------------------
// Vision-direction attention + fused column sum-exp (fixed reference m=0).
// ---------------------------------------------------------------------------
__global__ __launch_bounds__(256, 3) void attn_fwd_v(
    const bf16* __restrict__ qv,   // [B*NV][2048], q = cols 0..1023 (scale folded in W)
    const bf16* __restrict__ kv,   // [B*NL][2048], k = cols 0..1023
    const bf16* __restrict__ vlT,  // [B*H][HD][NL]
    const int* __restrict__ mask,  // [B][NL]
    bf16* __restrict__ ovh,        // [B*NV][E]
    float* __restrict__ sfin) {    // [64 bh][256] column sum-exp (pre-zeroed)
  __shared__ short kp_lds[256 * 72];  // k tile (stride 72, mask in pad) -> P (stride 268) -> out (stride 72)
  __shared__ float stf[1024];         // [4 wave][256 col] partial column sums
  const int tid = threadIdx.x, wave = tid >> 6, lane = tid & 63;
  const int qt = blockIdx.x, bh = blockIdx.y;
  const int b = bh >> 4, h = bh & 15;
  const size_t qrow0 = (size_t)b * NVTOK + qt * 64;
  const size_t krow0 = (size_t)b * NLTOK;
  const int rl = lane & 15, lg = lane >> 4;

#pragma unroll
  for (int it = 0; it < 8; it++) {
    int vv = it * 256 + tid;
    int nl = vv >> 3, c = vv & 7;
    *(bf16x8*)&kp_lds[nl * 72 + c * 8] =
        *(const bf16x8*)((const short*)kv + (krow0 + nl) * 2048 + h * HD + c * 8);
  }
  kp_lds[tid * 72 + 64] = (short)(mask[b * NLTOK + tid] != 0);  // mask in row pads
  __syncthreads();  // bar1: k tile + mask visible

  floatx4 sacc[16];
#pragma unroll
  for (int ct = 0; ct < 16; ct++) sacc[ct] = (floatx4){0.f, 0.f, 0.f, 0.f};
  const short* qrow = (const short*)qv + (qrow0 + wave * 16 + rl) * 2048 + h * HD;
  bf16x8 a0 = *(const bf16x8*)(qrow + lg * 8);
  bf16x8 a1 = *(const bf16x8*)(qrow + 32 + lg * 8);
#pragma unroll
  for (int ct = 0; ct < 16; ct++) {
    bf16x8 b0 = *(const bf16x8*)&kp_lds[(ct * 16 + rl) * 72 + lg * 8];
    bf16x8 b1 = *(const bf16x8*)&kp_lds[(ct * 16 + rl) * 72 + 32 + lg * 8];
    sacc[ct] = MFMA(a0, b0, sacc[ct]);
    sacc[ct] = MFMA(a1, b1, sacc[ct]);
  }

  // Preload this wave's 8 vlT fragments (d-slice wave*16..) — latency hides
  // under the softmax below.
  const short* vbase = (const short*)vlT + ((size_t)bh * 64 + wave * 16) * 256;
  bf16x8 vfr[8];
#pragma unroll
  for (int ks = 0; ks < 8; ks++)
    vfr[ks] = *(const bf16x8*)(vbase + (size_t)rl * 256 + ks * 32 + lg * 8);

  // pre-mask column sum-exp (reference 0) partials
#pragma unroll
  for (int ct = 0; ct < 16; ct++) {
    float s = __expf(sacc[ct][0]) + __expf(sacc[ct][1]) +
              __expf(sacc[ct][2]) + __expf(sacc[ct][3]);
    s += __shfl_xor(s, 16);
    s += __shfl_xor(s, 32);
    if (lane < 16) stf[wave * 256 + ct * 16 + lane] = s;
  }

  // mask bias (from k-row pads; intact until bar2)
  float mb[16];
#pragma unroll
  for (int ct = 0; ct < 16; ct++)
    mb[ct] = kp_lds[(ct * 16 + rl) * 72 + 64] ? 0.0f : -1e9f;

  // masked row softmax, in registers (rows = wave*16 + lg*4 + r, cols = ct*16 + rl)
  float rmax[4] = {-1e30f, -1e30f, -1e30f, -1e30f};
#pragma unroll
  for (int ct = 0; ct < 16; ct++)
#pragma unroll
    for (int r = 0; r < 4; r++) {
      sacc[ct][r] += mb[ct];
      rmax[r] = fmaxf(rmax[r], sacc[ct][r]);
    }
#pragma unroll
  for (int r = 0; r < 4; r++) {
    rmax[r] = fmaxf(rmax[r], __shfl_xor(rmax[r], 1));
    rmax[r] = fmaxf(rmax[r], __shfl_xor(rmax[r], 2));
    rmax[r] = fmaxf(rmax[r], __shfl_xor(rmax[r], 4));
    rmax[r] = fmaxf(rmax[r], __shfl_xor(rmax[r], 8));
  }
  float rsum[4] = {0.f, 0.f, 0.f, 0.f};
#pragma unroll
  for (int ct = 0; ct < 16; ct++)
#pragma unroll
    for (int r = 0; r < 4; r++) {
      sacc[ct][r] = __expf(sacc[ct][r] - rmax[r]);
      rsum[r] += sacc[ct][r];
    }
#pragma unroll
  for (int r = 0; r < 4; r++) {
    rsum[r] += __shfl_xor(rsum[r], 1);
    rsum[r] += __shfl_xor(rsum[r], 2);
    rsum[r] += __shfl_xor(rsum[r], 4);
    rsum[r] += __shfl_xor(rsum[r], 8);
    rsum[r] = 1.0f / fmaxf(rsum[r], 1e-20f);
  }
  __syncthreads();  // bar2: all k reads + stf writes done; P may overwrite k

  // merge 4 waves' column partials -> global atomic
  {
    float s = stf[tid] + stf[256 + tid] + stf[512 + tid] + stf[768 + tid];
    atomicAdd(&sfin[(size_t)bh * 256 + tid], s);
  }

  // write P (bf16), stride 268 shorts
#pragma unroll
  for (int ct = 0; ct < 16; ct++)
#pragma unroll
    for (int r = 0; r < 4; r++)
      kp_lds[(wave * 16 + lg * 4 + r) * 268 + ct * 16 + rl] = f2bs(sacc[ct][r] * rsum[r]);
  __syncthreads();  // bar3: P visible to all waves

  // PV: wave computes out[mt*16+..][wave*16 + rl] for all 4 m-tiles
  floatx4 oacc[4];
#pragma unroll
  for (int mt = 0; mt < 4; mt++) oacc[mt] = (floatx4){0.f, 0.f, 0.f, 0.f};
#pragma unroll
  for (int ks = 0; ks < 8; ks++) {
#pragma unroll
    for (int mt = 0; mt < 4; mt++) {
      bf16x8 af = *(const bf16x8*)&kp_lds[(mt * 16 + rl) * 268 + ks * 32 + lg * 8];
      oacc[mt] = MFMA(af, vfr[ks], oacc[mt]);
    }
  }
  __syncthreads();  // bar4: all PV reads of P done

  // stage out tile [64 q][64 d] (stride 72 shorts)
#pragma unroll
  for (int mt = 0; mt < 4; mt++)
#pragma unroll
    for (int r = 0; r < 4; r++)
      kp_lds[(mt * 16 + lg * 4 + r) * 72 + wave * 16 + rl] = f2bs(oacc[mt][r]);
  __syncthreads();  // bar5: out tile visible

  // coalesced store: 2 x b128 per thread
#pragma unroll
  for (int pass = 0; pass < 2; pass++) {
    int idx = pass * 256 + tid;
    int row = idx >> 3, c = idx & 7;
    bf16x8 o = *(const bf16x8*)&kp_lds[row * 72 + c * 8];
    *(bf16x8*)((short*)ovh + (qrow0 + row) * EMBED + h * HD + c * 8) = o;
  }
}

__global__ void zero_f32(float* __restrict__ p, int n) {
  int i = blockIdx.x * 256 + threadIdx.x;
  if (i < n) p[i] = 0.f;
}

// ---------------------------------------------------------------------------
// Language-direction attention: per block (512 q rows, one bh).
// ---------------------------------------------------------------------------
__global__ __launch_bounds__(256) void attn_fwd_l(
    const bf16* __restrict__ qv,  // [B*NV][2048], q cols 0..1023, val_v cols 1024..2047
    const bf16* __restrict__ kv,  // [B*NL][2048], k = cols 0..1023
    const float* __restrict__ sf, // [64 bh][256] column sum-exp
    float* __restrict__ olacc) {  // [B*NL][E] fp32, pre-zeroed
  __shared__ short k_lds[256 * 72];
  __shared__ short PT[256 * 40];
  __shared__ short vvT[64 * 40];
  __shared__ float sl[256];
  const int tid = threadIdx.x, wave = tid >> 6, lane = tid & 63;
  const int chunk = blockIdx.x, bh = blockIdx.y;
  const int b = bh >> 4, h = bh & 15;
  const size_t krow0 = (size_t)b * NLTOK;
  const size_t qbase = (size_t)b * NVTOK + chunk * 512;
  const int rl = lane & 15, lg = lane >> 4;

#pragma unroll
  for (int it = 0; it < 8; it++) {
    int vvi = it * 256 + tid;
    int nl = vvi >> 3, c = vvi & 7;
    *(bf16x8*)&k_lds[nl * 72 + c * 8] =
        *(const bf16x8*)((const short*)kv + (krow0 + nl) * 2048 + h * HD + c * 8);
  }
  sl[tid] = 1.0f / fmaxf(sf[(size_t)bh * 256 + tid], 1e-20f);
  __syncthreads();

  floatx4 acc[4][4];
#pragma unroll
  for (int rt = 0; rt < 4; rt++)
#pragma unroll
    for (int dt = 0; dt < 4; dt++) acc[rt][dt] = (floatx4){0.f, 0.f, 0.f, 0.f};

  const int qrt = wave & 1, ctb = (wave >> 1) * 8;
  for (int qs = 0; qs < 16; qs++) {
    const short* qrow = (const short*)qv + (qbase + qs * 32 + qrt * 16 + rl) * 2048 + h * HD;
    bf16x8 a0 = *(const bf16x8*)(qrow + lg * 8);
    bf16x8 a1 = *(const bf16x8*)(qrow + 32 + lg * 8);
    floatx4 s8[8];
#pragma unroll
    for (int i = 0; i < 8; i++) {
      int ct = ctb + i;
      bf16x8 b0 = *(const bf16x8*)&k_lds[(ct * 16 + rl) * 72 + lg * 8];
      bf16x8 b1 = *(const bf16x8*)&k_lds[(ct * 16 + rl) * 72 + 32 + lg * 8];
      floatx4 s = (floatx4){0.f, 0.f, 0.f, 0.f};
      s = MFMA(a0, b0, s);
      s = MFMA(a1, b1, s);
      s8[i] = s;
    }
    __syncthreads();  // previous iteration's PT/vvT reads complete
#pragma unroll
    for (int i = 0; i < 8; i++) {
      int col = (ctb + i) * 16 + rl;
      float linv = sl[col];
#pragma unroll
      for (int r = 0; r < 4; r++)
        PT[col * 40 + qrt * 16 + lg * 4 + r] = f2bs(__expf(s8[i][r]) * linv);
    }
    {
      int qq = tid >> 3, c = tid & 7;
      bf16x8 vvv = *(const bf16x8*)((const short*)qv +
                                    (qbase + qs * 32 + qq) * 2048 + 1024 + h * HD + c * 8);
      const short* vp = (const short*)&vvv;
#pragma unroll
      for (int j = 0; j < 8; j++) vvT[(c * 8 + j) * 40 + qq] = vp[j];
    }
    __syncthreads();
#pragma unroll
    for (int rt = 0; rt < 4; rt++) {
      bf16x8 af = *(const bf16x8*)&PT[(wave * 64 + rt * 16 + rl) * 40 + lg * 8];
#pragma unroll
      for (int dt = 0; dt < 4; dt++) {
        bf16x8 bfr = *(const bf16x8*)&vvT[(dt * 16 + rl) * 40 + lg * 8];
        acc[rt][dt] = MFMA(af, bfr, acc[rt][dt]);
      }
    }
  }
#pragma unroll
  for (int rt = 0; rt < 4; rt++)
#pragma unroll
    for (int dt = 0; dt < 4; dt++)
#pragma unroll
      for (int r = 0; r < 4; r++) {
        int nl = wave * 64 + rt * 16 + lg * 4 + r;
        int d = dt * 16 + rl;
        atomicAdd(&olacc[((size_t)b * NLTOK + nl) * EMBED + h * HD + d], acc[rt][dt][r]);
      }
}

__global__ void finalize_out_l(const float* __restrict__ olacc, bf16* __restrict__ olh) {
  int i = blockIdx.x * 256 + threadIdx.x;
  if (i < 1024 * 1024) olh[i] = __float2bfloat16(olacc[i]);
}

// ---------------------------------------------------------------------------
extern "C" void kernel_launch(void* const* d_in, const int* in_sizes, int n_in,
                              void* d_out, int out_size, void* d_ws, size_t ws_size,
                              hipStream_t stream) {
  (void)in_sizes; (void)n_in; (void)out_size; (void)ws_size;
  const void* v_raw = d_in[0];
  const void* l_raw = d_in[1];
  const int*  mask  = (const int*)d_in[2];
  const void* W_v2q = d_in[3];  const void* b_v2q = d_in[4];
  const void* W_l2k = d_in[5];  const void* b_l2k = d_in[6];
  const void* W_v2v = d_in[7];  const void* b_v2v = d_in[8];
  const void* W_l2v = d_in[9];  const void* b_l2v = d_in[10];
  const void* W_v2o = d_in[11]; const void* b_v2o = d_in[12];
  const void* W_l2o = d_in[13]; const void* b_l2o = d_in[14];

  static bool lds_attr_ok = false;
  if (!lds_attr_ok) {
    hipFuncSetAttribute((const void*)gemm256b_nt,
                        hipFuncAttributeMaxDynamicSharedMemorySize, 98304);
    lds_attr_ok = true;
  }

  char* ws = (char*)d_ws;
  size_t off = 0;
  auto alloc = [&](size_t bytes) -> void* {
    void* p = ws + off;
    off += (bytes + 255) & ~(size_t)255;
    return p;
  };
  int*  flag   = (int*)alloc(256);
  bf16* vb     = (bf16*)alloc((size_t)16777216 * 2);  // later aliased by ovh
  bf16* lb     = (bf16*)alloc((size_t)786432 * 2);
  bf16* b_qv   = (bf16*)alloc(4096);   // [2048] = bq | bvv (bq pre-scaled)
  bf16* b_kvl  = (bf16*)alloc(4096);   // [2048] = bk | bvl
  bf16* bov    = (bf16*)alloc(2048);
  bf16* bol    = (bf16*)alloc(1536);
  bf16* Wqv    = (bf16*)alloc((size_t)2048 * 1024 * 2);  // [2048][1024] v2q(scaled)|v2v
  bf16* Wkvl   = (bf16*)alloc((size_t)2048 * 768 * 2);   // [2048][768]  l2k|l2v
  bf16* Wt_v2o = (bf16*)alloc((size_t)1024 * 1024 * 2);
  bf16* Wt_l2o = (bf16*)alloc((size_t)768 * 1024 * 2);
  bf16* qvb    = (bf16*)alloc((size_t)16384 * 2048 * 2); // merged q|val_v
  bf16* kvb    = (bf16*)alloc((size_t)1024 * 2048 * 2);  // merged k|val_l
  bf16* vlT    = (bf16*)alloc((size_t)64 * 64 * 256 * 2);
  float* sfin  = (float*)alloc((size_t)64 * 256 * 4);      // contiguous with olacc
  float* olacc = (float*)alloc((size_t)1024 * 1024 * 4);
  bf16* olh    = (bf16*)alloc((size_t)1024 * 1024 * 2);
  bf16* ovh    = vb;  // vb dead after v-projection

  detect_dtype<<<1, 256, 0, stream>>>((const unsigned*)v_raw, flag);

  convert_to_bf16_v4<<<16384, 256, 0, stream>>>(v_raw, vb, 4194304, flag);
  convert_to_bf16_v4<<<768, 256, 0, stream>>>(l_raw, lb, 196608, flag);

  BArgs ba;
  ba.src[0] = b_v2q; ba.dst[0] = b_qv;         ba.n[0] = 1024; ba.scale[0] = QSCALE;
  ba.src[1] = b_l2k; ba.dst[1] = b_kvl;        ba.n[1] = 1024; ba.scale[1] = 1.0f;
  ba.src[2] = b_v2v; ba.dst[2] = b_qv + 1024;  ba.n[2] = 1024; ba.scale[2] = 1.0f;
  ba.src[3] = b_l2v; ba.dst[3] = b_kvl + 1024; ba.n[3] = 1024; ba.scale[3] = 1.0f;
  ba.src[4] = b_v2o; ba.dst[4] = bov;          ba.n[4] = 1024; ba.scale[4] = 1.0f;
  ba.src[5] = b_l2o; ba.dst[5] = bol;          ba.n[5] = 768;  ba.scale[5] = 1.0f;
  convert_bias_all<<<dim3(4, 6), 256, 0, stream>>>(ba, flag);

  WTArgs wa;
  wa.src[0] = W_v2q; wa.dst[0] = Wqv;                     wa.R[0] = 1024; wa.C[0] = 1024; wa.scale[0] = QSCALE;
  wa.src[1] = W_l2k; wa.dst[1] = Wkvl;                    wa.R[1] = 768;  wa.C[1] = 1024; wa.scale[1] = 1.0f;
  wa.src[2] = W_v2v; wa.dst[2] = Wqv + (size_t)1024*1024; wa.R[2] = 1024; wa.C[2] = 1024; wa.scale[2] = 1.0f;
  wa.src[3] = W_l2v; wa.dst[3] = Wkvl + (size_t)1024*768; wa.R[3] = 768;  wa.C[3] = 1024; wa.scale[3] = 1.0f;
  wa.src[4] = W_v2o; wa.dst[4] = Wt_v2o;                  wa.R[4] = 1024; wa.C[4] = 1024; wa.scale[4] = 1.0f;
  wa.src[5] = W_l2o; wa.dst[5] = Wt_l2o;                  wa.R[5] = 1024; wa.C[5] = 768;  wa.scale[5] = 1.0f;
  convert_transpose_all<<<dim3(1024, 6), 256, 0, stream>>>(wa, flag);

  // zero sfin+olacc in one pass (contiguous in ws)
  zero_f32<<<4161, 256, 0, stream>>>(sfin, 64 * 256 + 1024 * 1024);

  const int* bf16out = flag + 1;  // constant 0
  // merged projections: [v] -> q|val_v via 256x128 deep-pipe, [l] -> k|val_l
  gemm256b_nt<<<1024, 512, 98304, stream>>>(vb, Wqv, b_qv, qvb, 0, 16384, 2048, 1024, 1.0f, bf16out);
  gemm_nt<<<dim3(8, 16), 256, 0, stream>>>(lb, Wkvl, b_kvl, kvb, 0, 1024, 2048, 768, 1.0f, bf16out);
  transpose_vl_heads<<<dim3(4, 64), 256, 0, stream>>>(kvb, vlT);

  // attention (vb is dead now; ovh aliases it)
  attn_fwd_v<<<dim3(64, 64), 256, 0, stream>>>(qvb, kvb, vlT, mask, ovh, sfin);
  attn_fwd_l<<<dim3(8, 64), 256, 0, stream>>>(qvb, kvb, sfin, olacc);
  finalize_out_l<<<4096, 256, 0, stream>>>(olacc, olh);

  // output projections straight into d_out (dtype per flag)
  gemm256b_nt<<<512, 512, 98304, stream>>>(ovh, Wt_v2o, bov, d_out, 0, 16384, 1024, 1024, 1.0f, flag);
  gemm_nt<<<dim3(8, 6), 256, 0, stream>>>(olh, Wt_l2o, bol, d_out, 16777216LL, 1024, 768, 1024, 1.0f, flag);
}

// Round 8
// 449.916 us; speedup vs baseline: 1.4046x; 1.0562x over previous
//
#include <hip/hip_runtime.h>
#include <hip/hip_bf16.h>

#define EMBED 1024
#define HEADS 16
#define HD 64
#define NVTOK 4096
#define NLTOK 256
#define BATCH 4
#define QSCALE 0.25f   // HEADS**-0.5

typedef __hip_bfloat16 bf16;
typedef __attribute__((ext_vector_type(8))) short bf16x8;
typedef __attribute__((ext_vector_type(4))) float floatx4;

#define MFMA(a, b, c) __builtin_amdgcn_mfma_f32_16x16x32_bf16((a), (b), (c), 0, 0, 0)

static __device__ __forceinline__ short f2bs(float x) {
  bf16 h = __float2bfloat16(x);
  return *reinterpret_cast<short*>(&h);
}
static __device__ __forceinline__ float b2f(bf16 x) { return __bfloat162float(x); }

// Async global->LDS, 16B per lane. LDS dest = wave-uniform base + lane*16.
typedef const __attribute__((address_space(1))) char ga_char;
typedef __attribute__((address_space(3))) char ls_char;
static __device__ __forceinline__ void load_lds16(const void* g, void* lds) {
  __builtin_amdgcn_global_load_lds((ga_char*)g, (ls_char*)(unsigned)(size_t)(lds), 16, 0, 0);
}

// ---------------------------------------------------------------------------
// Input dtype detector (fp32 vs bf16 packed). flag[0]=1 => fp32.
// ---------------------------------------------------------------------------
__global__ void detect_dtype(const unsigned* __restrict__ v, int* __restrict__ flag) {
  __shared__ int cnt;
  if (threadIdx.x == 0) cnt = 0;
  __syncthreads();
  unsigned u = v[threadIdx.x];
  int mid = (int)((u >> 7) & 0xFF);
  if (mid >= 110 && mid <= 140) atomicAdd(&cnt, 1);
  __syncthreads();
  if (threadIdx.x == 0) {
    flag[0] = (cnt < 192) ? 1 : 0;
    flag[1] = 0;
  }
}

// ---------------------------------------------------------------------------
// Vectorized input convert (4 elements/thread). n4 = n/4.
// ---------------------------------------------------------------------------
__global__ void convert_to_bf16_v4(const void* __restrict__ src, bf16* __restrict__ dst,
                                   int n4, const int* __restrict__ flag) {
  int i = blockIdx.x * 256 + threadIdx.x;
  if (i >= n4) return;
  short4 o;
  if (flag[0]) {
    float4 f = ((const float4*)src)[i];
    o.x = f2bs(f.x); o.y = f2bs(f.y); o.z = f2bs(f.z); o.w = f2bs(f.w);
  } else {
    o = ((const short4*)src)[i];
  }
  ((short4*)dst)[i] = o;
}

// Batched weight convert+transpose (+ per-weight scale): src [R][C] -> dst [C][R].
struct WTArgs {
  const void* src[6];
  bf16* dst[6];
  int R[6];
  int C[6];
  float scale[6];
};
__global__ __launch_bounds__(256) void convert_transpose_all(WTArgs a, const int* __restrict__ flag) {
  __shared__ float tile[32][33];
  const int z = blockIdx.y;
  const int R = a.R[z], C = a.C[z];
  const float sc = a.scale[z];
  const int tpc = C >> 5;
  const int nt = (R >> 5) * tpc;
  const int t = blockIdx.x;
  if (t >= nt) return;
  const int r0 = (t / tpc) << 5, c0 = (t % tpc) << 5;
  {
    const int row = threadIdx.x >> 3, cg = (threadIdx.x & 7) << 2;
    if (flag[0]) {
      float4 f = *(const float4*)((const float*)a.src[z] + (size_t)(r0 + row) * C + c0 + cg);
      tile[row][cg] = f.x * sc; tile[row][cg + 1] = f.y * sc;
      tile[row][cg + 2] = f.z * sc; tile[row][cg + 3] = f.w * sc;
    } else {
      short4 f = *(const short4*)((const short*)a.src[z] + (size_t)(r0 + row) * C + c0 + cg);
      tile[row][cg]     = b2f(*(const bf16*)&f.x) * sc;
      tile[row][cg + 1] = b2f(*(const bf16*)&f.y) * sc;
      tile[row][cg + 2] = b2f(*(const bf16*)&f.z) * sc;
      tile[row][cg + 3] = b2f(*(const bf16*)&f.w) * sc;
    }
  }
  __syncthreads();
  {
    const int col = threadIdx.x >> 3, rg = (threadIdx.x & 7) << 2;
    short4 o;
    o.x = f2bs(tile[rg + 0][col]);
    o.y = f2bs(tile[rg + 1][col]);
    o.z = f2bs(tile[rg + 2][col]);
    o.w = f2bs(tile[rg + 3][col]);
    *(short4*)((short*)a.dst[z] + (size_t)(c0 + col) * R + r0 + rg) = o;
  }
}

// Batched bias convert (+ scale).
struct BArgs {
  const void* src[6];
  bf16* dst[6];
  int n[6];
  float scale[6];
};
__global__ void convert_bias_all(BArgs a, const int* __restrict__ flag) {
  int z = blockIdx.y;
  int i = blockIdx.x * 256 + threadIdx.x;
  if (i >= a.n[z]) return;
  float x = flag[0] ? ((const float*)a.src[z])[i] : b2f(((const bf16*)a.src[z])[i]);
  a.dst[z][i] = __float2bfloat16(x * a.scale[z]);
}

// ---------------------------------------------------------------------------
// val_l per-head transpose: vl = kv[:, 1024:2048] -> vlT [B*H][HD][NL]
// ---------------------------------------------------------------------------
__global__ __launch_bounds__(256) void transpose_vl_heads(const bf16* __restrict__ kv,
                                                          bf16* __restrict__ vlT) {
  __shared__ short t[64][72];
  const int bh = blockIdx.y, b = bh >> 4, h = bh & 15;
  const int nl0 = blockIdx.x << 6;
  const int tid = threadIdx.x;
  {
    const int nl = tid >> 2, dg = (tid & 3) << 4;
    const short* s = (const short*)kv + ((size_t)b * NLTOK + nl0 + nl) * 2048 + 1024 + h * HD + dg;
    *(bf16x8*)&t[nl][dg]     = *(const bf16x8*)s;
    *(bf16x8*)&t[nl][dg + 8] = *(const bf16x8*)(s + 8);
  }
  __syncthreads();
  {
    const int d = tid >> 2, ng = (tid & 3) << 4;
    short* o = (short*)vlT + ((size_t)bh * HD + d) * NLTOK + nl0 + ng;
    short tmp[16];
#pragma unroll
    for (int j = 0; j < 16; j++) tmp[j] = t[ng + j][d];
    *(bf16x8*)o       = *(bf16x8*)&tmp[0];
    *(bf16x8*)(o + 8) = *(bf16x8*)&tmp[8];
  }
}

// ---------------------------------------------------------------------------
// Small/medium NT GEMM (m97 128x128 pattern, BK=64, LDS-staged epilogue).
// Used for the small l-side GEMMs.
// ---------------------------------------------------------------------------
__global__ __launch_bounds__(256) void gemm_nt(
    const bf16* __restrict__ A, const bf16* __restrict__ Bt,
    const bf16* __restrict__ bias, void* __restrict__ Cout, long long coff,
    int M, int N, int K, float alpha, const int* __restrict__ outf) {
  __shared__ short lds_all[16896];
  short* As = lds_all;
  short* Bs = lds_all + 8192;
  const int f32o = outf[0];
  const int tid = threadIdx.x;
  const int wave = tid >> 6, lane = tid & 63;
  const int bm = blockIdx.x * 128, bn = blockIdx.y * 128;
  const int wr = (wave & 1) * 64, wc = (wave >> 1) * 64;
  const int rl = lane & 15, kg = (lane >> 4) * 8;

  const int srow = wave * 16 + (lane >> 2);
  const int scol = (lane & 3) * 8;
  const short* Ag = (const short*)A + (size_t)(bm + srow) * K + scol;
  const short* Bg = (const short*)Bt + (size_t)(bn + srow) * K + scol;
  short* As0l = &As[wave * 512];
  short* As1l = &As[2048 + wave * 512];
  short* As0h = &As[4096 + wave * 512];
  short* As1h = &As[6144 + wave * 512];
  short* Bs0l = &Bs[wave * 512];
  short* Bs1l = &Bs[2048 + wave * 512];
  short* Bs0h = &Bs[4096 + wave * 512];
  short* Bs1h = &Bs[6144 + wave * 512];
  const size_t rstep = (size_t)64 * K;

  floatx4 acc[4][4];
#pragma unroll
  for (int i = 0; i < 4; i++)
#pragma unroll
    for (int j = 0; j < 4; j++) acc[i][j] = (floatx4){0.f, 0.f, 0.f, 0.f};

  for (int k0 = 0; k0 < K; k0 += 64) {
    __syncthreads();
    load_lds16(Ag + k0, As0l);
    load_lds16(Ag + rstep + k0, As1l);
    load_lds16(Ag + k0 + 32, As0h);
    load_lds16(Ag + rstep + k0 + 32, As1h);
    load_lds16(Bg + k0, Bs0l);
    load_lds16(Bg + rstep + k0, Bs1l);
    load_lds16(Bg + k0 + 32, Bs0h);
    load_lds16(Bg + rstep + k0 + 32, Bs1h);
    __syncthreads();
#pragma unroll
    for (int half = 0; half < 2; half++) {
      const short* Ah = &As[half * 4096];
      const short* Bh = &Bs[half * 4096];
      bf16x8 af[4], bfr[4];
#pragma unroll
      for (int i = 0; i < 4; i++) af[i]  = *(const bf16x8*)&Ah[(wr + i * 16 + rl) * 32 + kg];
#pragma unroll
      for (int j = 0; j < 4; j++) bfr[j] = *(const bf16x8*)&Bh[(wc + j * 16 + rl) * 32 + kg];
#pragma unroll
      for (int i = 0; i < 4; i++)
#pragma unroll
        for (int j = 0; j < 4; j++) acc[i][j] = MFMA(af[i], bfr[j], acc[i][j]);
    }
  }

  const int rg = (lane >> 4) * 4;
  __syncthreads();  // all K-loop LDS reads done; reuse lds_all for C staging

  if (!f32o) {
#pragma unroll
    for (int j = 0; j < 4; j++) {
      float bv = b2f(bias[bn + wc + j * 16 + rl]);
#pragma unroll
      for (int i = 0; i < 4; i++)
#pragma unroll
        for (int r = 0; r < 4; r++)
          lds_all[(wr + i * 16 + rg + r) * 132 + wc + j * 16 + rl] =
              f2bs((acc[i][j][r] + bv) * alpha);
    }
    __syncthreads();
#pragma unroll
    for (int it = 0; it < 8; it++) {
      int idx = it * 256 + tid;
      int row = idx >> 4, c = idx & 15;
      bf16x8 o = *(const bf16x8*)&lds_all[row * 132 + c * 8];
      *(bf16x8*)((short*)Cout + coff + (long long)(bm + row) * N + bn + c * 8) = o;
    }
  } else {
    float* Cf = (float*)lds_all;
#pragma unroll
    for (int p = 0; p < 2; p++) {
      if ((wave & 1) == p) {
#pragma unroll
        for (int j = 0; j < 4; j++) {
          float bv = b2f(bias[bn + wc + j * 16 + rl]);
#pragma unroll
          for (int i = 0; i < 4; i++)
#pragma unroll
            for (int r = 0; r < 4; r++)
              Cf[(i * 16 + rg + r) * 132 + wc + j * 16 + rl] = (acc[i][j][r] + bv) * alpha;
        }
      }
      __syncthreads();
#pragma unroll
      for (int it = 0; it < 8; it++) {
        int idx = it * 256 + tid;
        int row = idx >> 5, c = idx & 31;
        float4 o = *(const float4*)&Cf[row * 132 + c * 4];
        *(float4*)((float*)Cout + coff + (long long)(bm + p * 64 + row) * N + bn + c * 4) = o;
      }
      if (p == 0) __syncthreads();
    }
  }
}

// ---------------------------------------------------------------------------
// Big NT GEMM v4: 256x128 tile, BK=64, 512 threads (8 waves = 4M x 2N),
// per-wave 64x64 output, acc[4][4] = 64 regs. Counted-vmcnt staging kept
// from R7 (proven): vmcnt(6), never 0 in loop, double-buffered 96KiB LDS.
// R8 change: DE-LOCKSTEPPED inner tile. R7's per-phase barrier pairs
// serialized the LDS-read burst against the MFMA burst across all 8 waves
// (1 block/CU -> no other waves to fill the idle pipe; MfmaUtil 32%).
// Correctness only needs: (a) reads not before data staged = vmcnt(6) +
// leading barrier; (b) stage not before all waves' reads done = trailing
// barrier (reads complete before the wave's MFMAs, which complete before
// it reaches the barrier). Inside the tile: no fences -- compiler emits
// counted lgkmcnt per fragment, waves de-sync, LDS and MFMA pipes overlap
// across waves (m114). setprio dropped (m190: null without phase split).
// Both-sides XOR swizzle (0 bank conflicts). bn-fastest XCD-bijective
// block order (R7: FETCH 266->82MB). M%256==0, N%128==0, K%128==0.
// ---------------------------------------------------------------------------
#define VMCNT6() do { asm volatile("s_waitcnt vmcnt(6)" ::: "memory"); \
                      __builtin_amdgcn_sched_barrier(0); } while (0)
#define VMCNT0() do { asm volatile("s_waitcnt vmcnt(0)" ::: "memory"); \
                      __builtin_amdgcn_sched_barrier(0); } while (0)

static __device__ __forceinline__ void compute_tile256b(
    const short* __restrict__ Ab, const short* __restrict__ Bb,
    floatx4 (&acc)[4][4], int wm, int wn, int rl, int lg) {
  const int sw = rl & 7;
  bf16x8 a[4][2], b[4][2];
#define LDA(m, kk) (*(const bf16x8*)&Ab[(wm * 64 + (m) * 16 + rl) * 64 + ((((kk) * 4 + lg) ^ sw) * 8)])
#define LDB(n, kk) (*(const bf16x8*)&Bb[(wn * 64 + (n) * 16 + rl) * 64 + ((((kk) * 4 + lg) ^ sw) * 8)])
#pragma unroll
  for (int m = 0; m < 4; m++) { a[m][0] = LDA(m, 0); a[m][1] = LDA(m, 1); }
#pragma unroll
  for (int n = 0; n < 4; n++) { b[n][0] = LDB(n, 0); b[n][1] = LDB(n, 1); }
#pragma unroll
  for (int m = 0; m < 4; m++)
#pragma unroll
    for (int n = 0; n < 4; n++) {
      acc[m][n] = MFMA(a[m][0], b[n][0], acc[m][n]);
      acc[m][n] = MFMA(a[m][1], b[n][1], acc[m][n]);
    }
#undef LDA
#undef LDB
}

__global__ __launch_bounds__(512, 2) void gemm256b_nt(
    const bf16* __restrict__ A, const bf16* __restrict__ Bt,
    const bf16* __restrict__ bias, void* __restrict__ Cout, long long coff,
    int M, int N, int K, float alpha, const int* __restrict__ outf) {
  extern __shared__ short lds[];  // 98304 B = 49152 shorts
  short* A0 = lds;                // 16384 shorts (256x64)
  short* B0 = lds + 16384;        // 8192 shorts (128x64)
  short* A1 = lds + 24576;
  short* B1 = lds + 40960;
  const int f32o = outf[0];
  const int tid = threadIdx.x;
  const int wave = tid >> 6, lane = tid & 63;
  const int rl = lane & 15, lg = lane >> 4;
  const int wm = wave >> 1, wn = wave & 1;   // 4M x 2N wave grid

  // XCD-aware bijective swizzle (m204), bn-FASTEST within the chunk:
  // consecutive blocks share an A-panel (L2), sweep B (L3).
  const int nwg = gridDim.x;
  const int nNT = N >> 7;
  int orig = blockIdx.x;
  int qq = nwg >> 3, rr = nwg & 7, xcd = orig & 7, sidx = orig >> 3;
  int swz = (xcd < rr) ? (xcd * (qq + 1) + sidx)
                       : (rr * (qq + 1) + (xcd - rr) * qq + sidx);
  const int bm = (swz / nNT) * 256;
  const int bn = (swz % nNT) * 128;

  // staging: source col-group pre-swizzled (cg = (l&7) ^ (l>>3)) so
  // lds[row][slot] = global(row, slot ^ (row&7)); read side XORs the same.
  const int r8 = lane >> 3;
  const int cgs = (lane & 7) ^ r8;
  const short* ga = (const short*)A + (size_t)(bm + wave * 8 + r8) * K + cgs * 8;
  const short* gb = (const short*)Bt + (size_t)(bn + wave * 8 + r8) * K + cgs * 8;

#define STAGE(LA, LB, k0_) do {                                             \
    _Pragma("unroll")                                                       \
    for (int p = 0; p < 4; p++)                                             \
      load_lds16(ga + (size_t)(p * 64) * K + (k0_), (LA) + wave * 512 + p * 4096); \
    _Pragma("unroll")                                                       \
    for (int p = 0; p < 2; p++)                                             \
      load_lds16(gb + (size_t)(p * 64) * K + (k0_), (LB) + wave * 512 + p * 4096); \
  } while (0)

  floatx4 acc[4][4];
#pragma unroll
  for (int m = 0; m < 4; m++)
#pragma unroll
    for (int n = 0; n < 4; n++) acc[m][n] = (floatx4){0.f, 0.f, 0.f, 0.f};

  const int NT = K >> 6;  // even (K multiple of 128)
  STAGE(A0, B0, 0);
  STAGE(A1, B1, 64);
  int kt = 0;
  for (; kt + 2 < NT; kt += 2) {
    VMCNT6();  // tile kt landed (tile kt+1's 6 loads still in flight)
    __builtin_amdgcn_s_barrier();
    compute_tile256b(A0, B0, acc, wm, wn, rl, lg);
    __builtin_amdgcn_sched_barrier(0);
    __builtin_amdgcn_s_barrier();   // all waves' A0/B0 reads complete
    __builtin_amdgcn_sched_barrier(0);
    STAGE(A0, B0, (kt + 2) * 64);
    VMCNT6();
    __builtin_amdgcn_s_barrier();
    compute_tile256b(A1, B1, acc, wm, wn, rl, lg);
    __builtin_amdgcn_sched_barrier(0);
    __builtin_amdgcn_s_barrier();   // all waves' A1/B1 reads complete
    __builtin_amdgcn_sched_barrier(0);
    STAGE(A1, B1, (kt + 3) * 64);
  }
  VMCNT6();
  __builtin_amdgcn_s_barrier();
  compute_tile256b(A0, B0, acc, wm, wn, rl, lg);
  VMCNT0();
  __builtin_amdgcn_s_barrier();
  compute_tile256b(A1, B1, acc, wm, wn, rl, lg);
  __syncthreads();  // epilogue boundary; vmcnt already 0

  // Epilogue: stage C through LDS, fully coalesced 16B stores.
  if (!f32o) {
    // single pass: 256 x 128 bf16 tile, stride 136 shorts (69632 B < 98304)
#pragma unroll
    for (int n = 0; n < 4; n++) {
      float bv = b2f(bias[bn + wn * 64 + n * 16 + rl]);
#pragma unroll
      for (int m = 0; m < 4; m++)
#pragma unroll
        for (int r2 = 0; r2 < 4; r2++)
          lds[(wm * 64 + m * 16 + lg * 4 + r2) * 136 + wn * 64 + n * 16 + rl] =
              f2bs((acc[m][n][r2] + bv) * alpha);
    }
    __syncthreads();
#pragma unroll
    for (int it = 0; it < 8; it++) {
      int idx2 = it * 512 + tid;
      int row = idx2 >> 4, c = idx2 & 15;
      bf16x8 o = *(const bf16x8*)&lds[row * 136 + c * 8];
      *(bf16x8*)((short*)Cout + coff + (long long)(bm + row) * N + bn + c * 8) = o;
    }
  } else {
    // two 128-row passes, stride 132 floats (67584 B < 98304)
    float* Cf = (float*)lds;
#pragma unroll
    for (int pp = 0; pp < 2; pp++) {
      if ((wm >> 1) == pp) {
#pragma unroll
        for (int n = 0; n < 4; n++) {
          float bv = b2f(bias[bn + wn * 64 + n * 16 + rl]);
#pragma unroll
          for (int m = 0; m < 4; m++)
#pragma unroll
            for (int r2 = 0; r2 < 4; r2++)
              Cf[((wm & 1) * 64 + m * 16 + lg * 4 + r2) * 132 + wn * 64 + n * 16 + rl] =
                  (acc[m][n][r2] + bv) * alpha;
        }
      }
      __syncthreads();
#pragma unroll
      for (int it = 0; it < 8; it++) {
        int idx2 = it * 512 + tid;
        int row = idx2 >> 5, c = idx2 & 31;
        float4 o = *(const float4*)&Cf[row * 132 + c * 4];
        *(float4*)((float*)Cout + coff + (long long)(bm + pp * 128 + row) * N + bn + c * 4) = o;
      }
      __syncthreads();
    }
  }
#undef STAGE
}

// ---------------------------------------------------------------------------
// Vision-direction attention + fused column sum-exp (fixed reference m=0).
// ---------------------------------------------------------------------------
__global__ __launch_bounds__(256, 3) void attn_fwd_v(
    const bf16* __restrict__ qv,   // [B*NV][2048], q = cols 0..1023 (scale folded in W)
    const bf16* __restrict__ kv,   // [B*NL][2048], k = cols 0..1023
    const bf16* __restrict__ vlT,  // [B*H][HD][NL]
    const int* __restrict__ mask,  // [B][NL]
    bf16* __restrict__ ovh,        // [B*NV][E]
    float* __restrict__ sfin) {    // [64 bh][256] column sum-exp (pre-zeroed)
  __shared__ short kp_lds[256 * 72];  // k tile (stride 72, mask in pad) -> P (stride 268) -> out (stride 72)
  __shared__ float stf[1024];         // [4 wave][256 col] partial column sums
  const int tid = threadIdx.x, wave = tid >> 6, lane = tid & 63;
  const int qt = blockIdx.x, bh = blockIdx.y;
  const int b = bh >> 4, h = bh & 15;
  const size_t qrow0 = (size_t)b * NVTOK + qt * 64;
  const size_t krow0 = (size_t)b * NLTOK;
  const int rl = lane & 15, lg = lane >> 4;

#pragma unroll
  for (int it = 0; it < 8; it++) {
    int vv = it * 256 + tid;
    int nl = vv >> 3, c = vv & 7;
    *(bf16x8*)&kp_lds[nl * 72 + c * 8] =
        *(const bf16x8*)((const short*)kv + (krow0 + nl) * 2048 + h * HD + c * 8);
  }
  kp_lds[tid * 72 + 64] = (short)(mask[b * NLTOK + tid] != 0);  // mask in row pads
  __syncthreads();  // bar1: k tile + mask visible

  floatx4 sacc[16];
#pragma unroll
  for (int ct = 0; ct < 16; ct++) sacc[ct] = (floatx4){0.f, 0.f, 0.f, 0.f};
  const short* qrow = (const short*)qv + (qrow0 + wave * 16 + rl) * 2048 + h * HD;
  bf16x8 a0 = *(const bf16x8*)(qrow + lg * 8);
  bf16x8 a1 = *(const bf16x8*)(qrow + 32 + lg * 8);
#pragma unroll
  for (int ct = 0; ct < 16; ct++) {
    bf16x8 b0 = *(const bf16x8*)&kp_lds[(ct * 16 + rl) * 72 + lg * 8];
    bf16x8 b1 = *(const bf16x8*)&kp_lds[(ct * 16 + rl) * 72 + 32 + lg * 8];
    sacc[ct] = MFMA(a0, b0, sacc[ct]);
    sacc[ct] = MFMA(a1, b1, sacc[ct]);
  }

  // Preload this wave's 8 vlT fragments (d-slice wave*16..) — latency hides
  // under the softmax below.
  const short* vbase = (const short*)vlT + ((size_t)bh * 64 + wave * 16) * 256;
  bf16x8 vfr[8];
#pragma unroll
  for (int ks = 0; ks < 8; ks++)
    vfr[ks] = *(const bf16x8*)(vbase + (size_t)rl * 256 + ks * 32 + lg * 8);

  // pre-mask column sum-exp (reference 0) partials
#pragma unroll
  for (int ct = 0; ct < 16; ct++) {
    float s = __expf(sacc[ct][0]) + __expf(sacc[ct][1]) +
              __expf(sacc[ct][2]) + __expf(sacc[ct][3]);
    s += __shfl_xor(s, 16);
    s += __shfl_xor(s, 32);
    if (lane < 16) stf[wave * 256 + ct * 16 + lane] = s;
  }

  // mask bias (from k-row pads; intact until bar2)
  float mb[16];
#pragma unroll
  for (int ct = 0; ct < 16; ct++)
    mb[ct] = kp_lds[(ct * 16 + rl) * 72 + 64] ? 0.0f : -1e9f;

  // masked row softmax, in registers (rows = wave*16 + lg*4 + r, cols = ct*16 + rl)
  float rmax[4] = {-1e30f, -1e30f, -1e30f, -1e30f};
#pragma unroll
  for (int ct = 0; ct < 16; ct++)
#pragma unroll
    for (int r = 0; r < 4; r++) {
      sacc[ct][r] += mb[ct];
      rmax[r] = fmaxf(rmax[r], sacc[ct][r]);
    }
#pragma unroll
  for (int r = 0; r < 4; r++) {
    rmax[r] = fmaxf(rmax[r], __shfl_xor(rmax[r], 1));
    rmax[r] = fmaxf(rmax[r], __shfl_xor(rmax[r], 2));
    rmax[r] = fmaxf(rmax[r], __shfl_xor(rmax[r], 4));
    rmax[r] = fmaxf(rmax[r], __shfl_xor(rmax[r], 8));
  }
  float rsum[4] = {0.f, 0.f, 0.f, 0.f};
#pragma unroll
  for (int ct = 0; ct < 16; ct++)
#pragma unroll
    for (int r = 0; r < 4; r++) {
      sacc[ct][r] = __expf(sacc[ct][r] - rmax[r]);
      rsum[r] += sacc[ct][r];
    }
#pragma unroll
  for (int r = 0; r < 4; r++) {
    rsum[r] += __shfl_xor(rsum[r], 1);
    rsum[r] += __shfl_xor(rsum[r], 2);
    rsum[r] += __shfl_xor(rsum[r], 4);
    rsum[r] += __shfl_xor(rsum[r], 8);
    rsum[r] = 1.0f / fmaxf(rsum[r], 1e-20f);
  }
  __syncthreads();  // bar2: all k reads + stf writes done; P may overwrite k

  // merge 4 waves' column partials -> global atomic
  {
    float s = stf[tid] + stf[256 + tid] + stf[512 + tid] + stf[768 + tid];
    atomicAdd(&sfin[(size_t)bh * 256 + tid], s);
  }

  // write P (bf16), stride 268 shorts
#pragma unroll
  for (int ct = 0; ct < 16; ct++)
#pragma unroll
    for (int r = 0; r < 4; r++)
      kp_lds[(wave * 16 + lg * 4 + r) * 268 + ct * 16 + rl] = f2bs(sacc[ct][r] * rsum[r]);
  __syncthreads();  // bar3: P visible to all waves

  // PV: wave computes out[mt*16+..][wave*16 + rl] for all 4 m-tiles
  floatx4 oacc[4];
#pragma unroll
  for (int mt = 0; mt < 4; mt++) oacc[mt] = (floatx4){0.f, 0.f, 0.f, 0.f};
#pragma unroll
  for (int ks = 0; ks < 8; ks++) {
#pragma unroll
    for (int mt = 0; mt < 4; mt++) {
      bf16x8 af = *(const bf16x8*)&kp_lds[(mt * 16 + rl) * 268 + ks * 32 + lg * 8];
      oacc[mt] = MFMA(af, vfr[ks], oacc[mt]);
    }
  }
  __syncthreads();  // bar4: all PV reads of P done

  // stage out tile [64 q][64 d] (stride 72 shorts)
#pragma unroll
  for (int mt = 0; mt < 4; mt++)
#pragma unroll
    for (int r = 0; r < 4; r++)
      kp_lds[(mt * 16 + lg * 4 + r) * 72 + wave * 16 + rl] = f2bs(oacc[mt][r]);
  __syncthreads();  // bar5: out tile visible

  // coalesced store: 2 x b128 per thread
#pragma unroll
  for (int pass = 0; pass < 2; pass++) {
    int idx = pass * 256 + tid;
    int row = idx >> 3, c = idx & 7;
    bf16x8 o = *(const bf16x8*)&kp_lds[row * 72 + c * 8];
    *(bf16x8*)((short*)ovh + (qrow0 + row) * EMBED + h * HD + c * 8) = o;
  }
}

__global__ void zero_f32(float* __restrict__ p, int n) {
  int i = blockIdx.x * 256 + threadIdx.x;
  if (i < n) p[i] = 0.f;
}

// ---------------------------------------------------------------------------
// Language-direction attention: per block (512 q rows, one bh).
// ---------------------------------------------------------------------------
__global__ __launch_bounds__(256) void attn_fwd_l(
    const bf16* __restrict__ qv,  // [B*NV][2048], q cols 0..1023, val_v cols 1024..2047
    const bf16* __restrict__ kv,  // [B*NL][2048], k = cols 0..1023
    const float* __restrict__ sf, // [64 bh][256] column sum-exp
    float* __restrict__ olacc) {  // [B*NL][E] fp32, pre-zeroed
  __shared__ short k_lds[256 * 72];
  __shared__ short PT[256 * 40];
  __shared__ short vvT[64 * 40];
  __shared__ float sl[256];
  const int tid = threadIdx.x, wave = tid >> 6, lane = tid & 63;
  const int chunk = blockIdx.x, bh = blockIdx.y;
  const int b = bh >> 4, h = bh & 15;
  const size_t krow0 = (size_t)b * NLTOK;
  const size_t qbase = (size_t)b * NVTOK + chunk * 512;
  const int rl = lane & 15, lg = lane >> 4;

#pragma unroll
  for (int it = 0; it < 8; it++) {
    int vvi = it * 256 + tid;
    int nl = vvi >> 3, c = vvi & 7;
    *(bf16x8*)&k_lds[nl * 72 + c * 8] =
        *(const bf16x8*)((const short*)kv + (krow0 + nl) * 2048 + h * HD + c * 8);
  }
  sl[tid] = 1.0f / fmaxf(sf[(size_t)bh * 256 + tid], 1e-20f);
  __syncthreads();

  floatx4 acc[4][4];
#pragma unroll
  for (int rt = 0; rt < 4; rt++)
#pragma unroll
    for (int dt = 0; dt < 4; dt++) acc[rt][dt] = (floatx4){0.f, 0.f, 0.f, 0.f};

  const int qrt = wave & 1, ctb = (wave >> 1) * 8;
  for (int qs = 0; qs < 16; qs++) {
    const short* qrow = (const short*)qv + (qbase + qs * 32 + qrt * 16 + rl) * 2048 + h * HD;
    bf16x8 a0 = *(const bf16x8*)(qrow + lg * 8);
    bf16x8 a1 = *(const bf16x8*)(qrow + 32 + lg * 8);
    floatx4 s8[8];
#pragma unroll
    for (int i = 0; i < 8; i++) {
      int ct = ctb + i;
      bf16x8 b0 = *(const bf16x8*)&k_lds[(ct * 16 + rl) * 72 + lg * 8];
      bf16x8 b1 = *(const bf16x8*)&k_lds[(ct * 16 + rl) * 72 + 32 + lg * 8];
      floatx4 s = (floatx4){0.f, 0.f, 0.f, 0.f};
      s = MFMA(a0, b0, s);
      s = MFMA(a1, b1, s);
      s8[i] = s;
    }
    __syncthreads();  // previous iteration's PT/vvT reads complete
#pragma unroll
    for (int i = 0; i < 8; i++) {
      int col = (ctb + i) * 16 + rl;
      float linv = sl[col];
#pragma unroll
      for (int r = 0; r < 4; r++)
        PT[col * 40 + qrt * 16 + lg * 4 + r] = f2bs(__expf(s8[i][r]) * linv);
    }
    {
      int qq = tid >> 3, c = tid & 7;
      bf16x8 vvv = *(const bf16x8*)((const short*)qv +
                                    (qbase + qs * 32 + qq) * 2048 + 1024 + h * HD + c * 8);
      const short* vp = (const short*)&vvv;
#pragma unroll
      for (int j = 0; j < 8; j++) vvT[(c * 8 + j) * 40 + qq] = vp[j];
    }
    __syncthreads();
#pragma unroll
    for (int rt = 0; rt < 4; rt++) {
      bf16x8 af = *(const bf16x8*)&PT[(wave * 64 + rt * 16 + rl) * 40 + lg * 8];
#pragma unroll
      for (int dt = 0; dt < 4; dt++) {
        bf16x8 bfr = *(const bf16x8*)&vvT[(dt * 16 + rl) * 40 + lg * 8];
        acc[rt][dt] = MFMA(af, bfr, acc[rt][dt]);
      }
    }
  }
#pragma unroll
  for (int rt = 0; rt < 4; rt++)
#pragma unroll
    for (int dt = 0; dt < 4; dt++)
#pragma unroll
      for (int r = 0; r < 4; r++) {
        int nl = wave * 64 + rt * 16 + lg * 4 + r;
        int d = dt * 16 + rl;
        atomicAdd(&olacc[((size_t)b * NLTOK + nl) * EMBED + h * HD + d], acc[rt][dt][r]);
      }
}

__global__ void finalize_out_l(const float* __restrict__ olacc, bf16* __restrict__ olh) {
  int i = blockIdx.x * 256 + threadIdx.x;
  if (i < 1024 * 1024) olh[i] = __float2bfloat16(olacc[i]);
}

// ---------------------------------------------------------------------------
extern "C" void kernel_launch(void* const* d_in, const int* in_sizes, int n_in,
                              void* d_out, int out_size, void* d_ws, size_t ws_size,
                              hipStream_t stream) {
  (void)in_sizes; (void)n_in; (void)out_size; (void)ws_size;
  const void* v_raw = d_in[0];
  const void* l_raw = d_in[1];
  const int*  mask  = (const int*)d_in[2];
  const void* W_v2q = d_in[3];  const void* b_v2q = d_in[4];
  const void* W_l2k = d_in[5];  const void* b_l2k = d_in[6];
  const void* W_v2v = d_in[7];  const void* b_v2v = d_in[8];
  const void* W_l2v = d_in[9];  const void* b_l2v = d_in[10];
  const void* W_v2o = d_in[11]; const void* b_v2o = d_in[12];
  const void* W_l2o = d_in[13]; const void* b_l2o = d_in[14];

  static bool lds_attr_ok = false;
  if (!lds_attr_ok) {
    hipFuncSetAttribute((const void*)gemm256b_nt,
                        hipFuncAttributeMaxDynamicSharedMemorySize, 98304);
    lds_attr_ok = true;
  }

  char* ws = (char*)d_ws;
  size_t off = 0;
  auto alloc = [&](size_t bytes) -> void* {
    void* p = ws + off;
    off += (bytes + 255) & ~(size_t)255;
    return p;
  };
  int*  flag   = (int*)alloc(256);
  bf16* vb     = (bf16*)alloc((size_t)16777216 * 2);  // later aliased by ovh
  bf16* lb     = (bf16*)alloc((size_t)786432 * 2);
  bf16* b_qv   = (bf16*)alloc(4096);   // [2048] = bq | bvv (bq pre-scaled)
  bf16* b_kvl  = (bf16*)alloc(4096);   // [2048] = bk | bvl
  bf16* bov    = (bf16*)alloc(2048);
  bf16* bol    = (bf16*)alloc(1536);
  bf16* Wqv    = (bf16*)alloc((size_t)2048 * 1024 * 2);  // [2048][1024] v2q(scaled)|v2v
  bf16* Wkvl   = (bf16*)alloc((size_t)2048 * 768 * 2);   // [2048][768]  l2k|l2v
  bf16* Wt_v2o = (bf16*)alloc((size_t)1024 * 1024 * 2);
  bf16* Wt_l2o = (bf16*)alloc((size_t)768 * 1024 * 2);
  bf16* qvb    = (bf16*)alloc((size_t)16384 * 2048 * 2); // merged q|val_v
  bf16* kvb    = (bf16*)alloc((size_t)1024 * 2048 * 2);  // merged k|val_l
  bf16* vlT    = (bf16*)alloc((size_t)64 * 64 * 256 * 2);
  float* sfin  = (float*)alloc((size_t)64 * 256 * 4);      // contiguous with olacc
  float* olacc = (float*)alloc((size_t)1024 * 1024 * 4);
  bf16* olh    = (bf16*)alloc((size_t)1024 * 1024 * 2);
  bf16* ovh    = vb;  // vb dead after v-projection

  detect_dtype<<<1, 256, 0, stream>>>((const unsigned*)v_raw, flag);

  convert_to_bf16_v4<<<16384, 256, 0, stream>>>(v_raw, vb, 4194304, flag);
  convert_to_bf16_v4<<<768, 256, 0, stream>>>(l_raw, lb, 196608, flag);

  BArgs ba;
  ba.src[0] = b_v2q; ba.dst[0] = b_qv;         ba.n[0] = 1024; ba.scale[0] = QSCALE;
  ba.src[1] = b_l2k; ba.dst[1] = b_kvl;        ba.n[1] = 1024; ba.scale[1] = 1.0f;
  ba.src[2] = b_v2v; ba.dst[2] = b_qv + 1024;  ba.n[2] = 1024; ba.scale[2] = 1.0f;
  ba.src[3] = b_l2v; ba.dst[3] = b_kvl + 1024; ba.n[3] = 1024; ba.scale[3] = 1.0f;
  ba.src[4] = b_v2o; ba.dst[4] = bov;          ba.n[4] = 1024; ba.scale[4] = 1.0f;
  ba.src[5] = b_l2o; ba.dst[5] = bol;          ba.n[5] = 768;  ba.scale[5] = 1.0f;
  convert_bias_all<<<dim3(4, 6), 256, 0, stream>>>(ba, flag);

  WTArgs wa;
  wa.src[0] = W_v2q; wa.dst[0] = Wqv;                     wa.R[0] = 1024; wa.C[0] = 1024; wa.scale[0] = QSCALE;
  wa.src[1] = W_l2k; wa.dst[1] = Wkvl;                    wa.R[1] = 768;  wa.C[1] = 1024; wa.scale[1] = 1.0f;
  wa.src[2] = W_v2v; wa.dst[2] = Wqv + (size_t)1024*1024; wa.R[2] = 1024; wa.C[2] = 1024; wa.scale[2] = 1.0f;
  wa.src[3] = W_l2v; wa.dst[3] = Wkvl + (size_t)1024*768; wa.R[3] = 768;  wa.C[3] = 1024; wa.scale[3] = 1.0f;
  wa.src[4] = W_v2o; wa.dst[4] = Wt_v2o;                  wa.R[4] = 1024; wa.C[4] = 1024; wa.scale[4] = 1.0f;
  wa.src[5] = W_l2o; wa.dst[5] = Wt_l2o;                  wa.R[5] = 1024; wa.C[5] = 768;  wa.scale[5] = 1.0f;
  convert_transpose_all<<<dim3(1024, 6), 256, 0, stream>>>(wa, flag);

  // zero sfin+olacc in one pass (contiguous in ws)
  zero_f32<<<4161, 256, 0, stream>>>(sfin, 64 * 256 + 1024 * 1024);

  const int* bf16out = flag + 1;  // constant 0
  // merged projections: [v] -> q|val_v via 256x128 deep-pipe, [l] -> k|val_l
  gemm256b_nt<<<1024, 512, 98304, stream>>>(vb, Wqv, b_qv, qvb, 0, 16384, 2048, 1024, 1.0f, bf16out);
  gemm_nt<<<dim3(8, 16), 256, 0, stream>>>(lb, Wkvl, b_kvl, kvb, 0, 1024, 2048, 768, 1.0f, bf16out);
  transpose_vl_heads<<<dim3(4, 64), 256, 0, stream>>>(kvb, vlT);

  // attention (vb is dead now; ovh aliases it)
  attn_fwd_v<<<dim3(64, 64), 256, 0, stream>>>(qvb, kvb, vlT, mask, ovh, sfin);
  attn_fwd_l<<<dim3(8, 64), 256, 0, stream>>>(qvb, kvb, sfin, olacc);
  finalize_out_l<<<4096, 256, 0, stream>>>(olacc, olh);

  // output projections straight into d_out (dtype per flag)
  gemm256b_nt<<<512, 512, 98304, stream>>>(ovh, Wt_v2o, bov, d_out, 0, 16384, 1024, 1024, 1.0f, flag);
  gemm_nt<<<dim3(8, 6), 256, 0, stream>>>(olh, Wt_l2o, bol, d_out, 16777216LL, 1024, 768, 1024, 1.0f, flag);
}